// Round 6
// baseline (3215.186 us; speedup 1.0000x reference)
//
#include <hip/hip_runtime.h>
#include <hip/hip_bf16.h>
#include <math.h>

#define DEVI __device__ __forceinline__

static constexpr int BB = 32, NN = 2048, S1 = 512, S2 = 128;

// ---------------- static workspace layout (float units) ----------------
static constexpr size_t OFF_XS   = 0;
static constexpr size_t OFF_YS   = OFF_XS + (size_t)BB*NN;
static constexpr size_t OFF_ZS   = OFF_YS + (size_t)BB*NN;
static constexpr size_t OFF_SSQ  = OFF_ZS + (size_t)BB*NN;
static constexpr size_t OFF_NX1X = OFF_SSQ + (size_t)BB*NN;
static constexpr size_t OFF_NX1Y = OFF_NX1X + (size_t)BB*S1;
static constexpr size_t OFF_NX1Z = OFF_NX1Y + (size_t)BB*S1;
static constexpr size_t OFF_NX2X = OFF_NX1Z + (size_t)BB*S1;
static constexpr size_t OFF_NX2Y = OFF_NX2X + (size_t)BB*S2;
static constexpr size_t OFF_NX2Z = OFF_NX2Y + (size_t)BB*S2;
static constexpr size_t OFF_CODE = OFF_NX2Z + (size_t)BB*S2;          // 3*32*512
static constexpr size_t OFF_O3P  = OFF_CODE + (size_t)3*BB*512;       // 3*32*4*512
static constexpr size_t OFF_P1   = OFF_O3P + (size_t)3*BB*4*512;      // 3*(32*512)*128
static constexpr size_t OFF_X3   = OFF_P1 + (size_t)3*BB*S1*128;      // 3*4096*260
static constexpr size_t OFF_H3   = OFF_X3 + (size_t)3*BB*S2*260;      // 3*4096*512
static constexpr size_t OFF_W    = OFF_H3 + (size_t)3*BB*S2*512;
// weights (f32, padded)
static constexpr size_t W1A  = OFF_W;
static constexpr size_t B1A  = W1A + 3*64*6;
static constexpr size_t W2A  = B1A + 3*64;
static constexpr size_t B2A  = W2A + 3*128*64;
static constexpr size_t W1B  = B2A + 3*128;
static constexpr size_t B1B  = W1B + 3*128*132;
static constexpr size_t W2B  = B1B + 3*128;
static constexpr size_t B2B  = W2B + 3*256*128;
static constexpr size_t W1C  = B2B + 3*256;
static constexpr size_t B1C  = W1C + 3*512*260;
static constexpr size_t W2C  = B1C + 3*512;
static constexpr size_t B2C  = W2C + 3*512*512;
static constexpr size_t FW1  = B2C + 3*512;
static constexpr size_t FB1  = FW1 + 3*256*512;
static constexpr size_t FG1  = FB1 + 3*256;
static constexpr size_t FBE1 = FG1 + 3*256;
static constexpr size_t FW2  = FBE1 + 3*256;
static constexpr size_t FB2  = FW2 + 3*128*256;
static constexpr size_t FG2  = FB2 + 3*128;
static constexpr size_t FBE2 = FG2 + 3*128;
static constexpr size_t OFF_KNN1 = FBE2 + 3*128;                      // int region
static constexpr size_t OFF_KNN2 = OFF_KNN1 + (size_t)BB*S1*16;
static constexpr size_t WS_FLOATS = OFF_KNN2 + (size_t)BB*S2*48;      // ~18.67M floats = 74.7 MB

__device__ __align__(16) float g_ws[WS_FLOATS];
__device__ int g_is_f32;   // detector verdict: 1 = f32, 0 = bf16
__device__ int g_flip;     // 1 if pass-0 interpretation was bad and we re-converted flipped
__device__ int g_bad;      // scratch
__device__ int g_nz;       // scratch
__device__ int g_flags;    // diagnostic bits

DEVI float bf2f(const __hip_bfloat16 v){ return __bfloat162float(v); }
DEVI float rn_add(float a, float b){ return __fadd_rn(a,b); }
DEVI float rn_mul(float a, float b){ return __fmul_rn(a,b); }
DEVI float rn_sub(float a, float b){ return __fsub_rn(a,b); }
DEVI float sq3(float x,float y,float z){ return rn_add(rn_add(rn_mul(x,x),rn_mul(y,y)),rn_mul(z,z)); }

DEVI float ldany(const void* s, size_t i, int isf){
  return isf ? ((const float*)s)[i] : bf2f(((const __hip_bfloat16*)s)[i]);
}

// ---------------- init ----------------
__global__ __launch_bounds__(64) void init_flags_kernel(){
  if (threadIdx.x==0){ g_is_f32=0; g_flip=0; g_bad=0; g_nz=0; g_flags=0; }
}

// ---------------- dtype detection ----------------
__global__ __launch_bounds__(256) void detect_dtype_kernel(const void* __restrict__ pc){
  __shared__ int s_cnt[256];
  const unsigned short* h = (const unsigned short*)pc;
  int t = threadIdx.x; int weird = 0;
  for (int i=t; i<4096; i+=256){
    unsigned short v = h[2*i];
    int e = (v >> 7) & 0xFF;
    if (e == 0xFF || e < 90 || e > 140) weird++;
  }
  s_cnt[t] = weird; __syncthreads();
  for (int o=128;o>0;o>>=1){ if (t<o) s_cnt[t]+=s_cnt[t+o]; __syncthreads(); }
  if (t==0) g_is_f32 = (s_cnt[0] > 1024) ? 1 : 0;
}

// ---------------- param conversion (mode 0: verdict; mode 1: flipped, gated) ----------------
struct ParamPtrs { const void* p[20]; };

DEVI void cvt_arr(const void* s, float* d, int n, int g, int gs, int isf){
  for (int i=g;i<n;i+=gs) d[i] = ldany(s,i,isf);
}
DEVI void cvt_pad(const void* s, float* d, int rows, int cin, int cinp, int g, int gs, int isf){
  int tot = rows*cinp;
  for (int i=g;i<tot;i+=gs){ int r=i/cinp, c=i%cinp; d[i] = (c<cin)? ldany(s,(size_t)r*cin+c,isf) : 0.f; }
}

__global__ __launch_bounds__(256) void cvt_params_kernel(ParamPtrs pp, int mode){
  if (mode==1 && g_flip==0) return;
  const int isf = g_is_f32 ^ mode;
  int g = blockIdx.x*256 + threadIdx.x; int gs = gridDim.x*256;
  float* ws = g_ws;
  cvt_arr(pp.p[0],  ws+W1A, 3*64*6, g, gs, isf);
  cvt_arr(pp.p[1],  ws+B1A, 3*64, g, gs, isf);
  cvt_arr(pp.p[2],  ws+W2A, 3*128*64, g, gs, isf);
  cvt_arr(pp.p[3],  ws+B2A, 3*128, g, gs, isf);
  cvt_pad(pp.p[4],  ws+W1B, 3*128, 131, 132, g, gs, isf);
  cvt_arr(pp.p[5],  ws+B1B, 3*128, g, gs, isf);
  cvt_arr(pp.p[6],  ws+W2B, 3*256*128, g, gs, isf);
  cvt_arr(pp.p[7],  ws+B2B, 3*256, g, gs, isf);
  cvt_pad(pp.p[8],  ws+W1C, 3*512, 259, 260, g, gs, isf);
  cvt_arr(pp.p[9],  ws+B1C, 3*512, g, gs, isf);
  cvt_arr(pp.p[10], ws+W2C, 3*512*512, g, gs, isf);
  cvt_arr(pp.p[11], ws+B2C, 3*512, g, gs, isf);
  cvt_arr(pp.p[12], ws+FW1, 3*256*512, g, gs, isf);
  cvt_arr(pp.p[13], ws+FB1, 3*256, g, gs, isf);
  cvt_arr(pp.p[14], ws+FG1, 3*256, g, gs, isf);
  cvt_arr(pp.p[15], ws+FBE1,3*256, g, gs, isf);
  cvt_arr(pp.p[16], ws+FW2, 3*128*256, g, gs, isf);
  cvt_arr(pp.p[17], ws+FB2, 3*128, g, gs, isf);
  cvt_arr(pp.p[18], ws+FG2, 3*128, g, gs, isf);
  cvt_arr(pp.p[19], ws+FBE2,3*128, g, gs, isf);
}

__global__ __launch_bounds__(256) void prep_xyz_kernel(const void* __restrict__ pc, int mode){
  if (mode==1 && g_flip==0) return;
  const int isf = g_is_f32 ^ mode;
  int i = blockIdx.x*256 + threadIdx.x;   // 65536 total
  int b = i >> 11, n = i & 2047;
  float x = ldany(pc, (size_t)(b*3+0)*2048 + n, isf);
  float y = ldany(pc, (size_t)(b*3+1)*2048 + n, isf);
  float z = ldany(pc, (size_t)(b*3+2)*2048 + n, isf);
  g_ws[OFF_XS+i]=x; g_ws[OFF_YS+i]=y; g_ws[OFF_ZS+i]=z;
  g_ws[OFF_SSQ+i]=sq3(x,y,z);
}

// ---------------- sanity scan -> g_bad/g_nz ----------------
__global__ __launch_bounds__(256) void scan_check_kernel(size_t off, int n){
  int g = blockIdx.x*256 + threadIdx.x; int gs = gridDim.x*256;
  int bad=0, nz=0;
  for (int i=g;i<n;i+=gs){
    float v = g_ws[off + i];
    if (v != v || fabsf(v) > 1e4f) bad=1;
    if (fabsf(v) > 1e-20f) nz=1;
  }
  unsigned long long mb = __ballot(bad), mn = __ballot(nz);
  if ((threadIdx.x & 63)==0){
    if (mb) atomicOr(&g_bad, 1);
    if (mn) atomicOr(&g_nz, 1);
  }
}

__global__ __launch_bounds__(64) void resolve_flip_kernel(){
  if (threadIdx.x==0){
    g_flip = (g_bad || !g_nz) ? 1 : 0;
    g_bad = 0; g_nz = 0;
  }
}

// ---------------- post-pipeline diagnostics -> g_flags ----------------
__global__ __launch_bounds__(256) void scan_diag_kernel(size_t off, int n, int bit, int track_nz){
  int g = blockIdx.x*256 + threadIdx.x; int gs = gridDim.x*256;
  int bad=0, nz=0;
  for (int i=g;i<n;i+=gs){
    float v = g_ws[off + i];
    if (v != v || fabsf(v) > 1e30f) bad=1;
    if (fabsf(v) > 1e-20f) nz=1;
  }
  unsigned long long mb = __ballot(bad), mn = __ballot(nz);
  if ((threadIdx.x & 63)==0){
    if (mb) atomicOr(&g_flags, 1<<bit);
    if (track_nz && mn) atomicOr(&g_nz, 1);
  }
}
__global__ __launch_bounds__(256) void scan_idx_kernel(size_t off, int n, int limit, int bit){
  int g = blockIdx.x*256 + threadIdx.x; int gs = gridDim.x*256;
  int bad=0;
  const int* p = (const int*)(g_ws + off);
  for (int i=g;i<n;i+=gs){ int v=p[i]; if (v<0 || v>=limit) bad=1; }
  unsigned long long mb = __ballot(bad);
  if ((threadIdx.x & 63)==0 && mb) atomicOr(&g_flags, 1<<bit);
}

// corruption -> overwrite output chunk 0 with V = 1 + k/128 (f32 now).
__global__ __launch_bounds__(256) void diag_write_kernel(float* __restrict__ out, int out_size){
  int f = g_flags;
  int codebad = ((f>>5)&1) || (g_nz==0);
  int trigger = ((f>>2)&1) || ((f>>3)&1) || ((f>>4)&1) || codebad;
  if (!trigger) return;
  int k = 64 | (g_is_f32?1:0) | (g_flip?2:0) | (f & 0x1C) | (codebad?32:0);
  float V = 1.0f + (float)k/128.0f;
  for (int i=threadIdx.x; i<4096 && i<out_size; i+=256) out[i] = V;
}

// ---------------- FPS ----------------
__global__ __launch_bounds__(256) void fps1_kernel(){
  const int b = blockIdx.x, t = threadIdx.x;
  const float* xs = g_ws + OFF_XS + (size_t)b*NN;
  const float* ys = g_ws + OFF_YS + (size_t)b*NN;
  const float* zs = g_ws + OFF_ZS + (size_t)b*NN;
  float* nx = g_ws + OFF_NX1X + (size_t)b*S1;
  float* ny = g_ws + OFF_NX1Y + (size_t)b*S1;
  float* nz = g_ws + OFF_NX1Z + (size_t)b*S1;
  float px[8],py[8],pz[8],dist[8];
  #pragma unroll
  for (int j=0;j<8;j++){ int n=j*256+t; px[j]=xs[n]; py[j]=ys[n]; pz[j]=zs[n]; dist[j]=1e10f; }
  __shared__ float s_val[4]; __shared__ int s_idx[4]; __shared__ float s_pt[3];
  float lx = xs[0], ly = ys[0], lz = zs[0];
  if (t==0){ nx[0]=lx; ny[0]=ly; nz[0]=lz; }
  for (int i=1;i<S1;i++){
    float best=-1.f; int bidx=0;
    #pragma unroll
    for (int j=0;j<8;j++){
      float dx=rn_sub(px[j],lx), dy=rn_sub(py[j],ly), dz=rn_sub(pz[j],lz);
      float d = sq3(dx,dy,dz);
      float nd = fminf(dist[j], d); dist[j]=nd;
      if (nd > best){ best=nd; bidx=j*256+t; }
    }
    #pragma unroll
    for (int off=32; off>=1; off>>=1){
      float ov = __shfl_xor(best, off); int oi = __shfl_xor(bidx, off);
      if (ov > best || (ov == best && oi < bidx)){ best=ov; bidx=oi; }
    }
    if ((t&63)==0){ s_val[t>>6]=best; s_idx[t>>6]=bidx; }
    __syncthreads();
    best = s_val[0]; bidx = s_idx[0];
    #pragma unroll
    for (int w=1;w<4;w++){
      float ov=s_val[w]; int oi=s_idx[w];
      if (ov > best || (ov == best && oi < bidx)){ best=ov; bidx=oi; }
    }
    if (t == (bidx & 255)){
      int slot = bidx >> 8;
      float sx=0,sy=0,sz=0;
      #pragma unroll
      for (int j=0;j<8;j++) if (j==slot){ sx=px[j]; sy=py[j]; sz=pz[j]; }
      s_pt[0]=sx; s_pt[1]=sy; s_pt[2]=sz;
      nx[i]=sx; ny[i]=sy; nz[i]=sz;
    }
    __syncthreads();
    lx=s_pt[0]; ly=s_pt[1]; lz=s_pt[2];
  }
}

__global__ __launch_bounds__(64) void fps2_kernel(){
  const int b = blockIdx.x, t = threadIdx.x;
  const float* xs = g_ws + OFF_NX1X + (size_t)b*S1;
  const float* ys = g_ws + OFF_NX1Y + (size_t)b*S1;
  const float* zs = g_ws + OFF_NX1Z + (size_t)b*S1;
  float* nx = g_ws + OFF_NX2X + (size_t)b*S2;
  float* ny = g_ws + OFF_NX2Y + (size_t)b*S2;
  float* nz = g_ws + OFF_NX2Z + (size_t)b*S2;
  float px[8],py[8],pz[8],dist[8];
  #pragma unroll
  for (int j=0;j<8;j++){ int n=j*64+t; px[j]=xs[n]; py[j]=ys[n]; pz[j]=zs[n]; dist[j]=1e10f; }
  float lx = xs[0], ly = ys[0], lz = zs[0];
  if (t==0){ nx[0]=lx; ny[0]=ly; nz[0]=lz; }
  for (int i=1;i<S2;i++){
    float best=-1.f; int bidx=0;
    #pragma unroll
    for (int j=0;j<8;j++){
      float dx=rn_sub(px[j],lx), dy=rn_sub(py[j],ly), dz=rn_sub(pz[j],lz);
      float d = sq3(dx,dy,dz);
      float nd = fminf(dist[j], d); dist[j]=nd;
      if (nd > best){ best=nd; bidx=j*64+t; }
    }
    #pragma unroll
    for (int off=32; off>=1; off>>=1){
      float ov = __shfl_xor(best, off); int oi = __shfl_xor(bidx, off);
      if (ov > best || (ov == best && oi < bidx)){ best=ov; bidx=oi; }
    }
    int owner = bidx & 63, slot = bidx >> 6;
    float sx=0,sy=0,sz=0;
    #pragma unroll
    for (int j=0;j<8;j++) if (j==slot){ sx=px[j]; sy=py[j]; sz=pz[j]; }
    lx = __shfl(sx, owner); ly = __shfl(sy, owner); lz = __shfl(sz, owner);
    if (t==0){ nx[i]=lx; ny[i]=ly; nz[i]=lz; }
  }
}

// ---------------- KNN ----------------
__global__ __launch_bounds__(256) void knn1_kernel(){
  int wid = (blockIdx.x*256 + threadIdx.x) >> 6;   // 16384 centers
  int lane = threadIdx.x & 63;
  int b = wid >> 9;
  const float* xs = g_ws + OFF_XS + (size_t)b*NN;
  const float* ys = g_ws + OFF_YS + (size_t)b*NN;
  const float* zs = g_ws + OFF_ZS + (size_t)b*NN;
  const float* sq = g_ws + OFF_SSQ + (size_t)b*NN;
  float cx = g_ws[OFF_NX1X + wid], cy = g_ws[OFF_NX1Y + wid], cz = g_ws[OFF_NX1Z + wid];
  float sc = sq3(cx,cy,cz);
  float d[32];
  #pragma unroll
  for (int c=0;c<32;c++){
    int n = c*64 + lane;
    float x=xs[n], y=ys[n], z=zs[n];
    float dot = rn_add(rn_add(rn_mul(cx,x),rn_mul(cy,y)),rn_mul(cz,z));
    d[c] = rn_sub(rn_add(sc,sq[n]), rn_mul(2.f,dot));
  }
  unsigned sel=0;
  int* out = (int*)(g_ws + OFF_KNN1) + (size_t)wid*16;
  for (int r=0;r<16;r++){
    float bd=3.0e38f; int bi=0x7fffffff;
    #pragma unroll
    for (int c=0;c<32;c++){
      bool ok = ((sel>>c)&1u)==0u;
      if (ok && d[c] < bd){ bd=d[c]; bi=c*64+lane; }
    }
    #pragma unroll
    for (int off=32; off>=1; off>>=1){
      float od=__shfl_xor(bd,off); int oi=__shfl_xor(bi,off);
      if (od < bd || (od==bd && oi<bi)){ bd=od; bi=oi; }
    }
    if (lane == (bi & 63)) sel |= 1u << ((unsigned)(bi & 2047) >> 6);
    if (lane == 0) out[r] = bi;
  }
}

__global__ __launch_bounds__(256) void knn2_kernel(){
  int wid = (blockIdx.x*256 + threadIdx.x) >> 6;   // 4096 centers
  int lane = threadIdx.x & 63;
  int b = wid >> 7;
  const float* xs = g_ws + OFF_NX1X + (size_t)b*S1;
  const float* ys = g_ws + OFF_NX1Y + (size_t)b*S1;
  const float* zs = g_ws + OFF_NX1Z + (size_t)b*S1;
  float cx = g_ws[OFF_NX2X + wid], cy = g_ws[OFF_NX2Y + wid], cz = g_ws[OFF_NX2Z + wid];
  float sc = sq3(cx,cy,cz);
  float d[8];
  #pragma unroll
  for (int c=0;c<8;c++){
    int n = c*64 + lane;
    float x=xs[n], y=ys[n], z=zs[n];
    float sx = sq3(x,y,z);
    float dot = rn_add(rn_add(rn_mul(cx,x),rn_mul(cy,y)),rn_mul(cz,z));
    d[c] = rn_sub(rn_add(sc,sx), rn_mul(2.f,dot));
  }
  unsigned sel=0;
  int* out = (int*)(g_ws + OFF_KNN2) + (size_t)wid*48;
  for (int r=0;r<48;r++){
    float bd=3.0e38f; int bi=0x7fffffff;
    #pragma unroll
    for (int c=0;c<8;c++){
      bool ok = ((sel>>c)&1u)==0u;
      if (ok && d[c] < bd){ bd=d[c]; bi=c*64+lane; }
    }
    #pragma unroll
    for (int off=32; off>=1; off>>=1){
      float od=__shfl_xor(bd,off); int oi=__shfl_xor(bi,off);
      if (od < bd || (od==bd && oi<bi)){ bd=od; bi=oi; }
    }
    if (lane == (bi & 63)) sel |= 1u << ((unsigned)(bi & 511) >> 6);
    if (lane == 0) out[r] = bi;
  }
}

// ---------------- SA1 fused ----------------
__global__ __launch_bounds__(128) void sa1_kernel(){
  int br = blockIdx.y; int t = threadIdx.x;
  __shared__ float w1s[384]; __shared__ float b1s[64]; __shared__ float b2s[128];
  __shared__ float xg[96]; __shared__ float hs[1024]; __shared__ float ctr[3];
  __shared__ int idxg[16];
  const float* w1g = g_ws + W1A + (size_t)br*384;
  for (int i=t;i<384;i+=128) w1s[i]=w1g[i];
  if (t<64) b1s[t] = g_ws[B1A + br*64 + t];
  b2s[t] = g_ws[B2A + br*128 + t];
  float4 w2r[16];
  const float4* w2p = (const float4*)(g_ws + W2A + ((size_t)br*128 + t)*64);
  #pragma unroll
  for (int q=0;q<16;q++) w2r[q]=w2p[q];
  const int* kn = (const int*)(g_ws + OFF_KNN1);
  __syncthreads();
  for (int g=0; g<8; g++){
    int gid = blockIdx.x*8 + g; int b = gid >> 9;
    if (t<16) idxg[t] = kn[(size_t)gid*16 + t] & (NN-1);
    if (t<3)  ctr[t] = (t==0)? g_ws[OFF_NX1X+gid] : (t==1)? g_ws[OFF_NX1Y+gid] : g_ws[OFF_NX1Z+gid];
    __syncthreads();
    if (t<96){
      int k=t/6, cc=t%6; int idx = idxg[k]; size_t gl = (size_t)b*NN + idx;
      float v;
      if (cc<3){ const float* A = (cc==0)? g_ws+OFF_XS : (cc==1)? g_ws+OFF_YS : g_ws+OFF_ZS; v = A[gl] - ctr[cc]; }
      else { int c2=cc-3; const float* A = (c2==0)? g_ws+OFF_XS : (c2==1)? g_ws+OFF_YS : g_ws+OFF_ZS; v = A[gl]; }
      xg[t]=v;
    }
    __syncthreads();
    for (int e=t; e<1024; e+=128){
      int k=e>>6, h=e&63;
      float acc=b1s[h];
      #pragma unroll
      for (int c=0;c<6;c++) acc += xg[k*6+c]*w1s[h*6+c];
      hs[e] = fmaxf(acc,0.f);
    }
    __syncthreads();
    float m=-3.4e38f;
    for (int k=0;k<16;k++){
      const float4* hp = (const float4*)(hs + k*64);
      float acc=b2s[t];
      #pragma unroll
      for (int q=0;q<16;q++){ float4 h4=hp[q]; acc += h4.x*w2r[q].x + h4.y*w2r[q].y + h4.z*w2r[q].z + h4.w*w2r[q].w; }
      m=fmaxf(m,acc);
    }
    g_ws[OFF_P1 + ((size_t)br*16384 + gid)*128 + t] = m;
    __syncthreads();
  }
}

// ---------------- SA2 fully fused ----------------
template<int K>
__global__ __launch_bounds__(256) void sa2_fused_kernel(int br){
  const int g2 = blockIdx.x;
  const int b = g2 >> 7;
  const int t = threadIdx.x;
  __shared__ float X[K*132];
  __shared__ float H[K*128];
  __shared__ float ctr[3];
  __shared__ int idxs[K];
  const int* kn2 = (const int*)(g_ws + OFF_KNN2) + (size_t)g2*48;
  if (t < K) idxs[t] = kn2[t] & (S1-1);
  if (t < 3) ctr[t] = g_ws[(t==0?OFF_NX2X:(t==1?OFF_NX2Y:OFF_NX2Z)) + g2];
  __syncthreads();
  const float* p1b = g_ws + OFF_P1 + (size_t)br*16384*128;
  for (int e=t; e<K*132; e+=256){
    int k = e/132, j = e%132;
    int idx = idxs[k];
    float v;
    if (j < 3){
      const float* A = (j==0)? g_ws+OFF_NX1X : (j==1)? g_ws+OFF_NX1Y : g_ws+OFF_NX1Z;
      v = A[(size_t)b*S1 + idx] - ctr[j];
    } else if (j < 131){
      v = p1b[((size_t)b*S1 + idx)*128 + (j-3)];
    } else v = 0.f;
    X[e] = v;
  }
  __syncthreads();
  {
    const int h = t & 127, p = t >> 7;
    constexpr int KH = K/2;
    float acc[KH];
    #pragma unroll
    for (int i=0;i<KH;i++) acc[i]=0.f;
    const float* w = g_ws + W1B + ((size_t)br*128 + h)*132;
    for (int jt=0; jt<132; jt+=44){
      float4 wr[11]; const float4* wp = (const float4*)(w+jt);
      #pragma unroll
      for (int q=0;q<11;q++) wr[q]=wp[q];
      #pragma unroll
      for (int i=0;i<KH;i++){
        const float4* xp = (const float4*)(X + (p + 2*i)*132 + jt);
        #pragma unroll
        for (int q=0;q<11;q++){ float4 x4=xp[q]; acc[i] += x4.x*wr[q].x + x4.y*wr[q].y + x4.z*wr[q].z + x4.w*wr[q].w; }
      }
    }
    float bias = g_ws[B1B + br*128 + h];
    #pragma unroll
    for (int i=0;i<KH;i++) H[(p+2*i)*128 + h] = fmaxf(acc[i]+bias, 0.f);
  }
  __syncthreads();
  {
    float acc[K];
    #pragma unroll
    for (int k=0;k<K;k++) acc[k]=0.f;
    const float* w = g_ws + W2B + ((size_t)br*256 + t)*128;
    for (int jt=0; jt<128; jt+=32){
      float4 wr[8]; const float4* wp=(const float4*)(w+jt);
      #pragma unroll
      for (int q=0;q<8;q++) wr[q]=wp[q];
      #pragma unroll
      for (int k=0;k<K;k++){
        const float4* xp = (const float4*)(H + k*128 + jt);
        #pragma unroll
        for (int q=0;q<8;q++){ float4 x4=xp[q]; acc[k] += x4.x*wr[q].x + x4.y*wr[q].y + x4.z*wr[q].z + x4.w*wr[q].w; }
      }
    }
    float m=-3.4e38f;
    #pragma unroll
    for (int k=0;k<K;k++) m=fmaxf(m,acc[k]);
    m += g_ws[B2B + br*256 + t];
    float* X3row = g_ws + OFF_X3 + ((size_t)br*4096 + g2)*260;
    X3row[3+t] = m;
    if (t<3) X3row[t] = ctr[t];
    if (t==3) X3row[259] = 0.f;
  }
}

// ---------------- SA3 layer1 ----------------
__global__ __launch_bounds__(512) void sa3l1_kernel(){
  int br = blockIdx.y; int r0 = blockIdx.x*32; int t = threadIdx.x;
  __shared__ float Xt[32*52];
  const float* X3b = g_ws + OFF_X3 + (size_t)br*4096*260;
  const float* w = g_ws + W1C + ((size_t)br*512 + t)*260;
  float acc[32];
  #pragma unroll
  for (int r=0;r<32;r++) acc[r]=0.f;
  for (int jt=0; jt<260; jt+=52){
    for (int e=t; e<32*52; e+=512){ int r=e/52, j=e%52; Xt[e] = X3b[(size_t)(r0+r)*260 + jt + j]; }
    __syncthreads();
    float4 wr[13]; const float4* wp=(const float4*)(w+jt);
    #pragma unroll
    for (int q=0;q<13;q++) wr[q]=wp[q];
    #pragma unroll
    for (int r=0;r<32;r++){
      const float4* xp = (const float4*)(Xt + r*52);
      #pragma unroll
      for (int q=0;q<13;q++){ float4 x4=xp[q]; acc[r] += x4.x*wr[q].x + x4.y*wr[q].y + x4.z*wr[q].z + x4.w*wr[q].w; }
    }
    __syncthreads();
  }
  float bias = g_ws[B1C + br*512 + t];
  float* H3 = g_ws + OFF_H3 + (size_t)br*4096*512;
  #pragma unroll
  for (int r=0;r<32;r++) H3[(size_t)(r0+r)*512 + t] = fmaxf(acc[r]+bias, 0.f);
}

// ---------------- SA3 layer2 partial ----------------
__global__ __launch_bounds__(512) void sa3l2_kernel(){
  int br = blockIdx.y; int b = blockIdx.x>>2; int part = blockIdx.x&3; int t=threadIdx.x;
  int row0 = b*128 + part*32;
  __shared__ float Xt[32*32];
  const float* H3 = g_ws + OFF_H3 + (size_t)br*4096*512;
  const float* w = g_ws + W2C + ((size_t)br*512 + t)*512;
  float acc[32];
  #pragma unroll
  for (int r=0;r<32;r++) acc[r]=0.f;
  for (int jt=0; jt<512; jt+=32){
    for (int e=t; e<1024; e+=512){ int r=e>>5, j=e&31; Xt[e] = H3[(size_t)(row0+r)*512 + jt + j]; }
    __syncthreads();
    float4 wr[8]; const float4* wp=(const float4*)(w+jt);
    #pragma unroll
    for (int q=0;q<8;q++) wr[q]=wp[q];
    #pragma unroll
    for (int r=0;r<32;r++){
      const float4* xp = (const float4*)(Xt + r*32);
      #pragma unroll
      for (int q=0;q<8;q++){ float4 x4=xp[q]; acc[r] += x4.x*wr[q].x + x4.y*wr[q].y + x4.z*wr[q].z + x4.w*wr[q].w; }
    }
    __syncthreads();
  }
  float m=-3.4e38f;
  #pragma unroll
  for (int r=0;r<32;r++) m = fmaxf(m, acc[r]);
  g_ws[OFF_O3P + (((size_t)br*BB + b)*4 + part)*512 + t] = m;
}

// ---------------- combine (f32 out) ----------------
__global__ __launch_bounds__(256) void combine_kernel(float* __restrict__ out, int out_size){
  int i = blockIdx.x*256 + threadIdx.x;   // 49152
  int br = i >> 14; int rem = i & 16383; int b = rem >> 9; int o = i & 511;
  float m = -3.4e38f;
  #pragma unroll
  for (int p=0;p<4;p++){
    m = fmaxf(m, g_ws[OFF_O3P + (((size_t)br*BB + b)*4 + p)*512 + o]);
  }
  m += g_ws[B2C + br*512 + o];
  g_ws[OFF_CODE + i] = m;
  int oi = 3*BB*128 + i;
  if (oi < out_size) out[oi] = m;
}

// ---------------- FC head (f32 out) ----------------
__global__ __launch_bounds__(256) void fc_kernel(float* __restrict__ out, int out_size){
  int br = blockIdx.x >> 5; int b = blockIdx.x & 31; int t = threadIdx.x;
  __shared__ float xin[512]; __shared__ float x1s[256];
  const float* code = g_ws + OFF_CODE + ((size_t)br*BB + b)*512;
  xin[t] = code[t]; xin[t+256] = code[t+256];
  __syncthreads();
  const float s = (float)(1.0 / sqrt(1.0 + 1e-5));
  {
    const float4* wp = (const float4*)(g_ws + FW1 + ((size_t)br*256 + t)*512);
    const float4* xp = (const float4*)xin;
    float acc = 0.f;
    #pragma unroll 8
    for (int q=0;q<128;q++){ float4 w4=wp[q], x4=xp[q]; acc += w4.x*x4.x + w4.y*x4.y + w4.z*x4.z + w4.w*x4.w; }
    acc = (acc + g_ws[FB1 + br*256+t]) * s;
    acc = g_ws[FG1+br*256+t]*acc + g_ws[FBE1+br*256+t];
    x1s[t] = fmaxf(acc, 0.f);
  }
  __syncthreads();
  if (t < 128){
    const float4* wp = (const float4*)(g_ws + FW2 + ((size_t)br*128 + t)*256);
    const float4* xp = (const float4*)x1s;
    float acc=0.f;
    #pragma unroll 8
    for (int q=0;q<64;q++){ float4 w4=wp[q], x4=xp[q]; acc += w4.x*x4.x + w4.y*x4.y + w4.z*x4.z + w4.w*x4.w; }
    acc = (acc + g_ws[FB2+br*128+t])*s;
    acc = g_ws[FG2+br*128+t]*acc + g_ws[FBE2+br*128+t];
    int oi = ((size_t)br*BB + b)*128 + t;
    if (oi < out_size) out[oi] = fmaxf(acc,0.f);
  }
}

// ---------------- launch (R6: f32 OUTPUT; pipeline as R5) ----------------
extern "C" void kernel_launch(void* const* d_in, const int* in_sizes, int n_in,
                              void* d_out, int out_size, void* d_ws, size_t ws_size,
                              hipStream_t stream) {
  (void)d_ws; (void)ws_size;
  if (n_in < 21) return;
  if (in_sizes[0] != BB*3*NN) return;
  float* out = (float*)d_out;   // reference output dtype is float32

  ParamPtrs pp;
  for (int i=0;i<20;i++) pp.p[i] = d_in[i+1];

  init_flags_kernel<<<1,64,0,stream>>>();
  detect_dtype_kernel<<<1,256,0,stream>>>(d_in[0]);
  cvt_params_kernel<<<512,256,0,stream>>>(pp, 0);
  prep_xyz_kernel<<<(BB*NN)/256,256,0,stream>>>(d_in[0], 0);
  scan_check_kernel<<<128,256,0,stream>>>(OFF_XS, 3*BB*NN);
  scan_check_kernel<<<128,256,0,stream>>>(FW1, 3*256*512);
  resolve_flip_kernel<<<1,64,0,stream>>>();
  cvt_params_kernel<<<512,256,0,stream>>>(pp, 1);     // gated on g_flip
  prep_xyz_kernel<<<(BB*NN)/256,256,0,stream>>>(d_in[0], 1);

  fps1_kernel<<<BB,256,0,stream>>>();
  fps2_kernel<<<BB,64,0,stream>>>();
  knn1_kernel<<<4096,256,0,stream>>>();
  knn2_kernel<<<1024,256,0,stream>>>();
  sa1_kernel<<<dim3(2048,3),128,0,stream>>>();

  sa2_fused_kernel<16><<<4096,256,0,stream>>>(0);
  sa2_fused_kernel<32><<<4096,256,0,stream>>>(1);
  sa2_fused_kernel<48><<<4096,256,0,stream>>>(2);

  sa3l1_kernel<<<dim3(128,3),512,0,stream>>>();
  sa3l2_kernel<<<dim3(128,3),512,0,stream>>>();
  combine_kernel<<<192,256,0,stream>>>(out, out_size);
  fc_kernel<<<96,256,0,stream>>>(out, out_size);

  // post-pipeline diagnostics (only fire on corruption)
  scan_diag_kernel<<<128,256,0,stream>>>(OFF_XS, 3*BB*NN, 2, 0);
  scan_diag_kernel<<<128,256,0,stream>>>(FW1, 3*256*512, 3, 0);
  scan_idx_kernel<<<64,256,0,stream>>>(OFF_KNN1, BB*S1*16, NN, 4);
  scan_idx_kernel<<<64,256,0,stream>>>(OFF_KNN2, BB*S2*48, S1, 4);
  scan_diag_kernel<<<256,256,0,stream>>>(OFF_P1, 3*BB*S1*128, 4, 0);
  scan_diag_kernel<<<64,256,0,stream>>>(OFF_CODE, 3*BB*512, 5, 1);
  diag_write_kernel<<<1,256,0,stream>>>(out, out_size);
}

// Round 7
// 2058.256 us; speedup vs baseline: 1.5621x; 1.5621x over previous
//
#include <hip/hip_runtime.h>
#include <hip/hip_bf16.h>
#include <math.h>

#define DEVI __device__ __forceinline__

static constexpr int BB = 32, NN = 2048, S1 = 512, S2 = 128;

typedef float f32x4 __attribute__((ext_vector_type(4)));
typedef short s16x8 __attribute__((ext_vector_type(8)));   // 8 bf16 bit-patterns (4 VGPRs)

// ---------------- static workspace layout (float units) ----------------
static constexpr size_t OFF_XS   = 0;
static constexpr size_t OFF_YS   = OFF_XS + (size_t)BB*NN;
static constexpr size_t OFF_ZS   = OFF_YS + (size_t)BB*NN;
static constexpr size_t OFF_SSQ  = OFF_ZS + (size_t)BB*NN;
static constexpr size_t OFF_NX1X = OFF_SSQ + (size_t)BB*NN;
static constexpr size_t OFF_NX1Y = OFF_NX1X + (size_t)BB*S1;
static constexpr size_t OFF_NX1Z = OFF_NX1Y + (size_t)BB*S1;
static constexpr size_t OFF_NX2X = OFF_NX1Z + (size_t)BB*S1;
static constexpr size_t OFF_NX2Y = OFF_NX2X + (size_t)BB*S2;
static constexpr size_t OFF_NX2Z = OFF_NX2Y + (size_t)BB*S2;
static constexpr size_t OFF_CODE = OFF_NX2Z + (size_t)BB*S2;          // 3*32*512
static constexpr size_t OFF_O3P  = OFF_CODE + (size_t)3*BB*512;       // 3*32*4*512
static constexpr size_t OFF_P1   = OFF_O3P + (size_t)3*BB*4*512;      // 3*(32*512)*128
static constexpr size_t OFF_X3   = OFF_P1 + (size_t)3*BB*S1*128;      // 3*4096*260
static constexpr size_t OFF_H3   = OFF_X3 + (size_t)3*BB*S2*260;      // 3*4096*512
static constexpr size_t OFF_W    = OFF_H3 + (size_t)3*BB*S2*512;
// weights (f32, padded)
static constexpr size_t W1A  = OFF_W;
static constexpr size_t B1A  = W1A + 3*64*6;
static constexpr size_t W2A  = B1A + 3*64;
static constexpr size_t B2A  = W2A + 3*128*64;
static constexpr size_t W1B  = B2A + 3*128;
static constexpr size_t B1B  = W1B + 3*128*132;
static constexpr size_t W2B  = B1B + 3*128;
static constexpr size_t B2B  = W2B + 3*256*128;
static constexpr size_t W1C  = B2B + 3*256;
static constexpr size_t B1C  = W1C + 3*512*260;
static constexpr size_t W2C  = B1C + 3*512;
static constexpr size_t B2C  = W2C + 3*512*512;
static constexpr size_t FW1  = B2C + 3*512;
static constexpr size_t FB1  = FW1 + 3*256*512;
static constexpr size_t FG1  = FB1 + 3*256;
static constexpr size_t FBE1 = FG1 + 3*256;
static constexpr size_t FW2  = FBE1 + 3*256;
static constexpr size_t FB2  = FW2 + 3*128*256;
static constexpr size_t FG2  = FB2 + 3*128;
static constexpr size_t FBE2 = FG2 + 3*128;
static constexpr size_t OFF_KNN1 = FBE2 + 3*128;                      // int region
static constexpr size_t OFF_KNN2 = OFF_KNN1 + (size_t)BB*S1*16;
// bf16 weight copies for MFMA (stored as shorts inside the float array)
static constexpr size_t OFF_W1BF = OFF_KNN2 + (size_t)BB*S2*48;       // 3*128*160 bf16 = 30720 floats
static constexpr size_t OFF_W2BF = OFF_W1BF + 30720;                  // 3*256*128 bf16 = 49152 floats
static constexpr size_t WS_FLOATS = OFF_W2BF + 49152;

__device__ __align__(16) float g_ws[WS_FLOATS];
__device__ int g_is_f32;
__device__ int g_flip;
__device__ int g_bad;
__device__ int g_nz;

DEVI float bf2f(const __hip_bfloat16 v){ return __bfloat162float(v); }
DEVI float rn_add(float a, float b){ return __fadd_rn(a,b); }
DEVI float rn_mul(float a, float b){ return __fmul_rn(a,b); }
DEVI float rn_sub(float a, float b){ return __fsub_rn(a,b); }
DEVI float sq3(float x,float y,float z){ return rn_add(rn_add(rn_mul(x,x),rn_mul(y,y)),rn_mul(z,z)); }

DEVI float ldany(const void* s, size_t i, int isf){
  return isf ? ((const float*)s)[i] : bf2f(((const __hip_bfloat16*)s)[i]);
}
// f32 -> bf16 bits, round-to-nearest-even
DEVI unsigned short f2bf(float f){
  unsigned u = __float_as_uint(f);
  unsigned r = (u + 0x7FFFu + ((u>>16)&1u)) >> 16;
  return (unsigned short)r;
}
// MFMA via inline asm (type-ambiguity-proof); D==C accumulate in VGPRs
DEVI void mfma16(f32x4& d, s16x8 a, s16x8 b){
  asm volatile("v_mfma_f32_16x16x32_bf16 %0, %1, %2, %0" : "+v"(d) : "v"(a), "v"(b));
}
// MFMA D-read-by-VALU hazard guard (SW wait states)
DEVI void mfma_guard(f32x4& d){
  asm volatile("s_nop 7\n\ts_nop 7\n\ts_nop 2" : "+v"(d));
}

// ---------------- init ----------------
__global__ __launch_bounds__(64) void init_flags_kernel(){
  if (threadIdx.x==0){ g_is_f32=0; g_flip=0; g_bad=0; g_nz=0; }
}

// ---------------- dtype detection ----------------
__global__ __launch_bounds__(256) void detect_dtype_kernel(const void* __restrict__ pc){
  __shared__ int s_cnt[256];
  const unsigned short* h = (const unsigned short*)pc;
  int t = threadIdx.x; int weird = 0;
  for (int i=t; i<4096; i+=256){
    unsigned short v = h[2*i];
    int e = (v >> 7) & 0xFF;
    if (e == 0xFF || e < 90 || e > 140) weird++;
  }
  s_cnt[t] = weird; __syncthreads();
  for (int o=128;o>0;o>>=1){ if (t<o) s_cnt[t]+=s_cnt[t+o]; __syncthreads(); }
  if (t==0) g_is_f32 = (s_cnt[0] > 1024) ? 1 : 0;
}

// ---------------- param conversion ----------------
struct ParamPtrs { const void* p[20]; };

DEVI void cvt_arr(const void* s, float* d, int n, int g, int gs, int isf){
  for (int i=g;i<n;i+=gs) d[i] = ldany(s,i,isf);
}
DEVI void cvt_pad(const void* s, float* d, int rows, int cin, int cinp, int g, int gs, int isf){
  int tot = rows*cinp;
  for (int i=g;i<tot;i+=gs){ int r=i/cinp, c=i%cinp; d[i] = (c<cin)? ldany(s,(size_t)r*cin+c,isf) : 0.f; }
}

__global__ __launch_bounds__(256) void cvt_params_kernel(ParamPtrs pp, int mode){
  if (mode==1 && g_flip==0) return;
  const int isf = g_is_f32 ^ mode;
  int g = blockIdx.x*256 + threadIdx.x; int gs = gridDim.x*256;
  float* ws = g_ws;
  cvt_arr(pp.p[0],  ws+W1A, 3*64*6, g, gs, isf);
  cvt_arr(pp.p[1],  ws+B1A, 3*64, g, gs, isf);
  cvt_arr(pp.p[2],  ws+W2A, 3*128*64, g, gs, isf);
  cvt_arr(pp.p[3],  ws+B2A, 3*128, g, gs, isf);
  cvt_pad(pp.p[4],  ws+W1B, 3*128, 131, 132, g, gs, isf);
  cvt_arr(pp.p[5],  ws+B1B, 3*128, g, gs, isf);
  cvt_arr(pp.p[6],  ws+W2B, 3*256*128, g, gs, isf);
  cvt_arr(pp.p[7],  ws+B2B, 3*256, g, gs, isf);
  cvt_pad(pp.p[8],  ws+W1C, 3*512, 259, 260, g, gs, isf);
  cvt_arr(pp.p[9],  ws+B1C, 3*512, g, gs, isf);
  cvt_arr(pp.p[10], ws+W2C, 3*512*512, g, gs, isf);
  cvt_arr(pp.p[11], ws+B2C, 3*512, g, gs, isf);
  cvt_arr(pp.p[12], ws+FW1, 3*256*512, g, gs, isf);
  cvt_arr(pp.p[13], ws+FB1, 3*256, g, gs, isf);
  cvt_arr(pp.p[14], ws+FG1, 3*256, g, gs, isf);
  cvt_arr(pp.p[15], ws+FBE1,3*256, g, gs, isf);
  cvt_arr(pp.p[16], ws+FW2, 3*128*256, g, gs, isf);
  cvt_arr(pp.p[17], ws+FB2, 3*128, g, gs, isf);
  cvt_arr(pp.p[18], ws+FG2, 3*128, g, gs, isf);
  cvt_arr(pp.p[19], ws+FBE2,3*128, g, gs, isf);
}

__global__ __launch_bounds__(256) void prep_xyz_kernel(const void* __restrict__ pc, int mode){
  if (mode==1 && g_flip==0) return;
  const int isf = g_is_f32 ^ mode;
  int i = blockIdx.x*256 + threadIdx.x;
  int b = i >> 11, n = i & 2047;
  float x = ldany(pc, (size_t)(b*3+0)*2048 + n, isf);
  float y = ldany(pc, (size_t)(b*3+1)*2048 + n, isf);
  float z = ldany(pc, (size_t)(b*3+2)*2048 + n, isf);
  g_ws[OFF_XS+i]=x; g_ws[OFF_YS+i]=y; g_ws[OFF_ZS+i]=z;
  g_ws[OFF_SSQ+i]=sq3(x,y,z);
}

// ---------------- sanity scan -> g_bad/g_nz ----------------
__global__ __launch_bounds__(256) void scan_check_kernel(size_t off, int n){
  int g = blockIdx.x*256 + threadIdx.x; int gs = gridDim.x*256;
  int bad=0, nz=0;
  for (int i=g;i<n;i+=gs){
    float v = g_ws[off + i];
    if (v != v || fabsf(v) > 1e4f) bad=1;
    if (fabsf(v) > 1e-20f) nz=1;
  }
  unsigned long long mb = __ballot(bad), mn = __ballot(nz);
  if ((threadIdx.x & 63)==0){
    if (mb) atomicOr(&g_bad, 1);
    if (mn) atomicOr(&g_nz, 1);
  }
}

__global__ __launch_bounds__(64) void resolve_flip_kernel(){
  if (threadIdx.x==0){
    g_flip = (g_bad || !g_nz) ? 1 : 0;
    g_bad = 0; g_nz = 0;
  }
}

// ---------------- bf16 weight copies for SA2 MFMA ----------------
__global__ __launch_bounds__(256) void cvt_bf16_kernel(){
  int g = blockIdx.x*256 + threadIdx.x; int gs = gridDim.x*256;
  unsigned short* w1d = (unsigned short*)(g_ws + OFF_W1BF);
  for (int i=g; i<3*128*160; i+=gs){
    int br = i/(128*160); int rem = i%(128*160); int h = rem/160; int c = rem%160;
    float v = (c<132) ? g_ws[W1B + ((size_t)br*128 + h)*132 + c] : 0.f;
    w1d[i] = f2bf(v);
  }
  unsigned short* w2d = (unsigned short*)(g_ws + OFF_W2BF);
  for (int i=g; i<3*256*128; i+=gs){
    w2d[i] = f2bf(g_ws[W2B + i]);
  }
}

// ---------------- FPS ----------------
__global__ __launch_bounds__(256) void fps1_kernel(){
  const int b = blockIdx.x, t = threadIdx.x;
  const float* xs = g_ws + OFF_XS + (size_t)b*NN;
  const float* ys = g_ws + OFF_YS + (size_t)b*NN;
  const float* zs = g_ws + OFF_ZS + (size_t)b*NN;
  float* nx = g_ws + OFF_NX1X + (size_t)b*S1;
  float* ny = g_ws + OFF_NX1Y + (size_t)b*S1;
  float* nz = g_ws + OFF_NX1Z + (size_t)b*S1;
  float px[8],py[8],pz[8],dist[8];
  #pragma unroll
  for (int j=0;j<8;j++){ int n=j*256+t; px[j]=xs[n]; py[j]=ys[n]; pz[j]=zs[n]; dist[j]=1e10f; }
  __shared__ float s_val[4]; __shared__ int s_idx[4]; __shared__ float s_pt[3];
  float lx = xs[0], ly = ys[0], lz = zs[0];
  if (t==0){ nx[0]=lx; ny[0]=ly; nz[0]=lz; }
  for (int i=1;i<S1;i++){
    float best=-1.f; int bidx=0;
    #pragma unroll
    for (int j=0;j<8;j++){
      float dx=rn_sub(px[j],lx), dy=rn_sub(py[j],ly), dz=rn_sub(pz[j],lz);
      float d = sq3(dx,dy,dz);
      float nd = fminf(dist[j], d); dist[j]=nd;
      if (nd > best){ best=nd; bidx=j*256+t; }
    }
    #pragma unroll
    for (int off=32; off>=1; off>>=1){
      float ov = __shfl_xor(best, off); int oi = __shfl_xor(bidx, off);
      if (ov > best || (ov == best && oi < bidx)){ best=ov; bidx=oi; }
    }
    if ((t&63)==0){ s_val[t>>6]=best; s_idx[t>>6]=bidx; }
    __syncthreads();
    best = s_val[0]; bidx = s_idx[0];
    #pragma unroll
    for (int w=1;w<4;w++){
      float ov=s_val[w]; int oi=s_idx[w];
      if (ov > best || (ov == best && oi < bidx)){ best=ov; bidx=oi; }
    }
    if (t == (bidx & 255)){
      int slot = bidx >> 8;
      float sx=0,sy=0,sz=0;
      #pragma unroll
      for (int j=0;j<8;j++) if (j==slot){ sx=px[j]; sy=py[j]; sz=pz[j]; }
      s_pt[0]=sx; s_pt[1]=sy; s_pt[2]=sz;
      nx[i]=sx; ny[i]=sy; nz[i]=sz;
    }
    __syncthreads();
    lx=s_pt[0]; ly=s_pt[1]; lz=s_pt[2];
  }
}

__global__ __launch_bounds__(64) void fps2_kernel(){
  const int b = blockIdx.x, t = threadIdx.x;
  const float* xs = g_ws + OFF_NX1X + (size_t)b*S1;
  const float* ys = g_ws + OFF_NX1Y + (size_t)b*S1;
  const float* zs = g_ws + OFF_NX1Z + (size_t)b*S1;
  float* nx = g_ws + OFF_NX2X + (size_t)b*S2;
  float* ny = g_ws + OFF_NX2Y + (size_t)b*S2;
  float* nz = g_ws + OFF_NX2Z + (size_t)b*S2;
  float px[8],py[8],pz[8],dist[8];
  #pragma unroll
  for (int j=0;j<8;j++){ int n=j*64+t; px[j]=xs[n]; py[j]=ys[n]; pz[j]=zs[n]; dist[j]=1e10f; }
  float lx = xs[0], ly = ys[0], lz = zs[0];
  if (t==0){ nx[0]=lx; ny[0]=ly; nz[0]=lz; }
  for (int i=1;i<S2;i++){
    float best=-1.f; int bidx=0;
    #pragma unroll
    for (int j=0;j<8;j++){
      float dx=rn_sub(px[j],lx), dy=rn_sub(py[j],ly), dz=rn_sub(pz[j],lz);
      float d = sq3(dx,dy,dz);
      float nd = fminf(dist[j], d); dist[j]=nd;
      if (nd > best){ best=nd; bidx=j*64+t; }
    }
    #pragma unroll
    for (int off=32; off>=1; off>>=1){
      float ov = __shfl_xor(best, off); int oi = __shfl_xor(bidx, off);
      if (ov > best || (ov == best && oi < bidx)){ best=ov; bidx=oi; }
    }
    int owner = bidx & 63, slot = bidx >> 6;
    float sx=0,sy=0,sz=0;
    #pragma unroll
    for (int j=0;j<8;j++) if (j==slot){ sx=px[j]; sy=py[j]; sz=pz[j]; }
    lx = __shfl(sx, owner); ly = __shfl(sy, owner); lz = __shfl(sz, owner);
    if (t==0){ nx[i]=lx; ny[i]=ly; nz[i]=lz; }
  }
}

// ---------------- KNN ----------------
__global__ __launch_bounds__(256) void knn1_kernel(){
  int wid = (blockIdx.x*256 + threadIdx.x) >> 6;
  int lane = threadIdx.x & 63;
  int b = wid >> 9;
  const float* xs = g_ws + OFF_XS + (size_t)b*NN;
  const float* ys = g_ws + OFF_YS + (size_t)b*NN;
  const float* zs = g_ws + OFF_ZS + (size_t)b*NN;
  const float* sq = g_ws + OFF_SSQ + (size_t)b*NN;
  float cx = g_ws[OFF_NX1X + wid], cy = g_ws[OFF_NX1Y + wid], cz = g_ws[OFF_NX1Z + wid];
  float sc = sq3(cx,cy,cz);
  float d[32];
  #pragma unroll
  for (int c=0;c<32;c++){
    int n = c*64 + lane;
    float x=xs[n], y=ys[n], z=zs[n];
    float dot = rn_add(rn_add(rn_mul(cx,x),rn_mul(cy,y)),rn_mul(cz,z));
    d[c] = rn_sub(rn_add(sc,sq[n]), rn_mul(2.f,dot));
  }
  unsigned sel=0;
  int* out = (int*)(g_ws + OFF_KNN1) + (size_t)wid*16;
  for (int r=0;r<16;r++){
    float bd=3.0e38f; int bi=0x7fffffff;
    #pragma unroll
    for (int c=0;c<32;c++){
      bool ok = ((sel>>c)&1u)==0u;
      if (ok && d[c] < bd){ bd=d[c]; bi=c*64+lane; }
    }
    #pragma unroll
    for (int off=32; off>=1; off>>=1){
      float od=__shfl_xor(bd,off); int oi=__shfl_xor(bi,off);
      if (od < bd || (od==bd && oi<bi)){ bd=od; bi=oi; }
    }
    if (lane == (bi & 63)) sel |= 1u << ((unsigned)(bi & 2047) >> 6);
    if (lane == 0) out[r] = bi;
  }
}

__global__ __launch_bounds__(256) void knn2_kernel(){
  int wid = (blockIdx.x*256 + threadIdx.x) >> 6;
  int lane = threadIdx.x & 63;
  int b = wid >> 7;
  const float* xs = g_ws + OFF_NX1X + (size_t)b*S1;
  const float* ys = g_ws + OFF_NX1Y + (size_t)b*S1;
  const float* zs = g_ws + OFF_NX1Z + (size_t)b*S1;
  float cx = g_ws[OFF_NX2X + wid], cy = g_ws[OFF_NX2Y + wid], cz = g_ws[OFF_NX2Z + wid];
  float sc = sq3(cx,cy,cz);
  float d[8];
  #pragma unroll
  for (int c=0;c<8;c++){
    int n = c*64 + lane;
    float x=xs[n], y=ys[n], z=zs[n];
    float sx = sq3(x,y,z);
    float dot = rn_add(rn_add(rn_mul(cx,x),rn_mul(cy,y)),rn_mul(cz,z));
    d[c] = rn_sub(rn_add(sc,sx), rn_mul(2.f,dot));
  }
  unsigned sel=0;
  int* out = (int*)(g_ws + OFF_KNN2) + (size_t)wid*48;
  for (int r=0;r<48;r++){
    float bd=3.0e38f; int bi=0x7fffffff;
    #pragma unroll
    for (int c=0;c<8;c++){
      bool ok = ((sel>>c)&1u)==0u;
      if (ok && d[c] < bd){ bd=d[c]; bi=c*64+lane; }
    }
    #pragma unroll
    for (int off=32; off>=1; off>>=1){
      float od=__shfl_xor(bd,off); int oi=__shfl_xor(bi,off);
      if (od < bd || (od==bd && oi<bi)){ bd=od; bi=oi; }
    }
    if (lane == (bi & 63)) sel |= 1u << ((unsigned)(bi & 511) >> 6);
    if (lane == 0) out[r] = bi;
  }
}

// ---------------- SA1 fused (unchanged f32) ----------------
__global__ __launch_bounds__(128) void sa1_kernel(){
  int br = blockIdx.y; int t = threadIdx.x;
  __shared__ float w1s[384]; __shared__ float b1s[64]; __shared__ float b2s[128];
  __shared__ float xg[96]; __shared__ float hs[1024]; __shared__ float ctr[3];
  __shared__ int idxg[16];
  const float* w1g = g_ws + W1A + (size_t)br*384;
  for (int i=t;i<384;i+=128) w1s[i]=w1g[i];
  if (t<64) b1s[t] = g_ws[B1A + br*64 + t];
  b2s[t] = g_ws[B2A + br*128 + t];
  float4 w2r[16];
  const float4* w2p = (const float4*)(g_ws + W2A + ((size_t)br*128 + t)*64);
  #pragma unroll
  for (int q=0;q<16;q++) w2r[q]=w2p[q];
  const int* kn = (const int*)(g_ws + OFF_KNN1);
  __syncthreads();
  for (int g=0; g<8; g++){
    int gid = blockIdx.x*8 + g; int b = gid >> 9;
    if (t<16) idxg[t] = kn[(size_t)gid*16 + t] & (NN-1);
    if (t<3)  ctr[t] = (t==0)? g_ws[OFF_NX1X+gid] : (t==1)? g_ws[OFF_NX1Y+gid] : g_ws[OFF_NX1Z+gid];
    __syncthreads();
    if (t<96){
      int k=t/6, cc=t%6; int idx = idxg[k]; size_t gl = (size_t)b*NN + idx;
      float v;
      if (cc<3){ const float* A = (cc==0)? g_ws+OFF_XS : (cc==1)? g_ws+OFF_YS : g_ws+OFF_ZS; v = A[gl] - ctr[cc]; }
      else { int c2=cc-3; const float* A = (c2==0)? g_ws+OFF_XS : (c2==1)? g_ws+OFF_YS : g_ws+OFF_ZS; v = A[gl]; }
      xg[t]=v;
    }
    __syncthreads();
    for (int e=t; e<1024; e+=128){
      int k=e>>6, h=e&63;
      float acc=b1s[h];
      #pragma unroll
      for (int c=0;c<6;c++) acc += xg[k*6+c]*w1s[h*6+c];
      hs[e] = fmaxf(acc,0.f);
    }
    __syncthreads();
    float m=-3.4e38f;
    for (int k=0;k<16;k++){
      const float4* hp = (const float4*)(hs + k*64);
      float acc=b2s[t];
      #pragma unroll
      for (int q=0;q<16;q++){ float4 h4=hp[q]; acc += h4.x*w2r[q].x + h4.y*w2r[q].y + h4.z*w2r[q].z + h4.w*w2r[q].w; }
      m=fmaxf(m,acc);
    }
    g_ws[OFF_P1 + ((size_t)br*16384 + gid)*128 + t] = m;
    __syncthreads();
  }
}

// ---------------- SA2 fused via MFMA bf16 ----------------
// layer1: H[K][128] = relu( X[K][160] * W1^T + b1 ), Kdim padded 132->160 (zeros)
// layer2: X3row[3+o] = max_k( H * W2^T )[k][o] + b2[o]
// LDS strides: X 168 shorts (336B, bank-safe), H 136 shorts (272B, bank-safe)
template<int K>
__global__ __launch_bounds__(256) void sa2_mfma_kernel(int br){
  constexpr int MT = K/16;
  const int g2 = blockIdx.x;
  const int b = g2 >> 7;
  const int t = threadIdx.x;
  const int wave = t >> 6, lane = t & 63, quad = lane >> 4, l16 = lane & 15;
  __shared__ __align__(16) short Xb[K*168];
  __shared__ __align__(16) short Hb[K*136];
  __shared__ float ctr[3];
  __shared__ int idxs[K];
  const int* kn2 = (const int*)(g_ws + OFF_KNN2) + (size_t)g2*48;
  if (t < K) idxs[t] = kn2[t] & (S1-1);
  if (t < 3) ctr[t] = g_ws[(t==0?OFF_NX2X:(t==1?OFF_NX2Y:OFF_NX2Z)) + g2];
  __syncthreads();
  const float* p1b = g_ws + OFF_P1 + (size_t)br*16384*128;
  for (int e=t; e<K*168; e+=256){
    int k = e/168, j = e%168;
    int idx = idxs[k];
    float v;
    if (j < 3){
      const float* A = (j==0)? g_ws+OFF_NX1X : (j==1)? g_ws+OFF_NX1Y : g_ws+OFF_NX1Z;
      v = A[(size_t)b*S1 + idx] - ctr[j];
    } else if (j < 131){
      v = p1b[((size_t)b*S1 + idx)*128 + (j-3)];
    } else v = 0.f;
    Xb[e] = (short)f2bf(v);
  }
  __syncthreads();
  // layer1: n-tiles 0..7 (128 hidden), 2 per wave; ksteps 5 (160)
  {
    const short* w1bf = (const short*)(g_ws + OFF_W1BF) + (size_t)br*128*160;
    const float* b1 = g_ws + B1B + br*128;
    for (int ni = wave; ni < 8; ni += 4){
      int h = ni*16 + l16;
      s16x8 bfr[5];
      #pragma unroll
      for (int ks=0;ks<5;ks++) bfr[ks] = *(const s16x8*)(w1bf + (size_t)h*160 + ks*32 + quad*8);
      float bias = b1[h];
      #pragma unroll
      for (int m=0; m<MT; m++){
        f32x4 acc = {0.f,0.f,0.f,0.f};
        #pragma unroll
        for (int ks=0;ks<5;ks++){
          s16x8 a = *(const s16x8*)(&Xb[(m*16 + l16)*168 + ks*32 + quad*8]);
          mfma16(acc, a, bfr[ks]);
        }
        mfma_guard(acc);
        #pragma unroll
        for (int r=0;r<4;r++){
          int row = m*16 + quad*4 + r;
          float hv = fmaxf(acc[r] + bias, 0.f);
          Hb[row*136 + ni*16 + l16] = (short)f2bf(hv);
        }
      }
    }
  }
  __syncthreads();
  // layer2: n-tiles 0..15 (256 outs), 4 per wave; ksteps 4 (128); max over K rows
  {
    const short* w2bf = (const short*)(g_ws + OFF_W2BF) + (size_t)br*256*128;
    const float* b2 = g_ws + B2B + br*256;
    float* X3row = g_ws + OFF_X3 + ((size_t)br*4096 + g2)*260;
    for (int ni = wave; ni < 16; ni += 4){
      int o = ni*16 + l16;
      s16x8 bfr[4];
      #pragma unroll
      for (int ks=0;ks<4;ks++) bfr[ks] = *(const s16x8*)(w2bf + (size_t)o*128 + ks*32 + quad*8);
      float vmax = -3.4e38f;
      #pragma unroll
      for (int m=0; m<MT; m++){
        f32x4 acc = {0.f,0.f,0.f,0.f};
        #pragma unroll
        for (int ks=0;ks<4;ks++){
          s16x8 a = *(const s16x8*)(&Hb[(m*16 + l16)*136 + ks*32 + quad*8]);
          mfma16(acc, a, bfr[ks]);
        }
        mfma_guard(acc);
        #pragma unroll
        for (int r=0;r<4;r++) vmax = fmaxf(vmax, acc[r]);
      }
      vmax = fmaxf(vmax, __shfl_xor(vmax, 16));
      vmax = fmaxf(vmax, __shfl_xor(vmax, 32));
      if (quad == 0) X3row[3 + o] = vmax + b2[o];
    }
    if (t < 3) X3row[t] = ctr[t];
    if (t == 3) X3row[259] = 0.f;
  }
}

// ---------------- SA3 layer1 (unchanged f32) ----------------
__global__ __launch_bounds__(512) void sa3l1_kernel(){
  int br = blockIdx.y; int r0 = blockIdx.x*32; int t = threadIdx.x;
  __shared__ float Xt[32*52];
  const float* X3b = g_ws + OFF_X3 + (size_t)br*4096*260;
  const float* w = g_ws + W1C + ((size_t)br*512 + t)*260;
  float acc[32];
  #pragma unroll
  for (int r=0;r<32;r++) acc[r]=0.f;
  for (int jt=0; jt<260; jt+=52){
    for (int e=t; e<32*52; e+=512){ int r=e/52, j=e%52; Xt[e] = X3b[(size_t)(r0+r)*260 + jt + j]; }
    __syncthreads();
    float4 wr[13]; const float4* wp=(const float4*)(w+jt);
    #pragma unroll
    for (int q=0;q<13;q++) wr[q]=wp[q];
    #pragma unroll
    for (int r=0;r<32;r++){
      const float4* xp = (const float4*)(Xt + r*52);
      #pragma unroll
      for (int q=0;q<13;q++){ float4 x4=xp[q]; acc[r] += x4.x*wr[q].x + x4.y*wr[q].y + x4.z*wr[q].z + x4.w*wr[q].w; }
    }
    __syncthreads();
  }
  float bias = g_ws[B1C + br*512 + t];
  float* H3 = g_ws + OFF_H3 + (size_t)br*4096*512;
  #pragma unroll
  for (int r=0;r<32;r++) H3[(size_t)(r0+r)*512 + t] = fmaxf(acc[r]+bias, 0.f);
}

// ---------------- SA3 layer2 partial (unchanged f32) ----------------
__global__ __launch_bounds__(512) void sa3l2_kernel(){
  int br = blockIdx.y; int b = blockIdx.x>>2; int part = blockIdx.x&3; int t=threadIdx.x;
  int row0 = b*128 + part*32;
  __shared__ float Xt[32*32];
  const float* H3 = g_ws + OFF_H3 + (size_t)br*4096*512;
  const float* w = g_ws + W2C + ((size_t)br*512 + t)*512;
  float acc[32];
  #pragma unroll
  for (int r=0;r<32;r++) acc[r]=0.f;
  for (int jt=0; jt<512; jt+=32){
    for (int e=t; e<1024; e+=512){ int r=e>>5, j=e&31; Xt[e] = H3[(size_t)(row0+r)*512 + jt + j]; }
    __syncthreads();
    float4 wr[8]; const float4* wp=(const float4*)(w+jt);
    #pragma unroll
    for (int q=0;q<8;q++) wr[q]=wp[q];
    #pragma unroll
    for (int r=0;r<32;r++){
      const float4* xp = (const float4*)(Xt + r*32);
      #pragma unroll
      for (int q=0;q<8;q++){ float4 x4=xp[q]; acc[r] += x4.x*wr[q].x + x4.y*wr[q].y + x4.z*wr[q].z + x4.w*wr[q].w; }
    }
    __syncthreads();
  }
  float m=-3.4e38f;
  #pragma unroll
  for (int r=0;r<32;r++) m = fmaxf(m, acc[r]);
  g_ws[OFF_O3P + (((size_t)br*BB + b)*4 + part)*512 + t] = m;
}

// ---------------- combine (f32 out) ----------------
__global__ __launch_bounds__(256) void combine_kernel(float* __restrict__ out, int out_size){
  int i = blockIdx.x*256 + threadIdx.x;
  int br = i >> 14; int rem = i & 16383; int b = rem >> 9; int o = i & 511;
  float m = -3.4e38f;
  #pragma unroll
  for (int p=0;p<4;p++){
    m = fmaxf(m, g_ws[OFF_O3P + (((size_t)br*BB + b)*4 + p)*512 + o]);
  }
  m += g_ws[B2C + br*512 + o];
  g_ws[OFF_CODE + i] = m;
  int oi = 3*BB*128 + i;
  if (oi < out_size) out[oi] = m;
}

// ---------------- FC head (f32 out) ----------------
__global__ __launch_bounds__(256) void fc_kernel(float* __restrict__ out, int out_size){
  int br = blockIdx.x >> 5; int b = blockIdx.x & 31; int t = threadIdx.x;
  __shared__ float xin[512]; __shared__ float x1s[256];
  const float* code = g_ws + OFF_CODE + ((size_t)br*BB + b)*512;
  xin[t] = code[t]; xin[t+256] = code[t+256];
  __syncthreads();
  const float s = (float)(1.0 / sqrt(1.0 + 1e-5));
  {
    const float4* wp = (const float4*)(g_ws + FW1 + ((size_t)br*256 + t)*512);
    const float4* xp = (const float4*)xin;
    float acc = 0.f;
    #pragma unroll 8
    for (int q=0;q<128;q++){ float4 w4=wp[q], x4=xp[q]; acc += w4.x*x4.x + w4.y*x4.y + w4.z*x4.z + w4.w*x4.w; }
    acc = (acc + g_ws[FB1 + br*256+t]) * s;
    acc = g_ws[FG1+br*256+t]*acc + g_ws[FBE1+br*256+t];
    x1s[t] = fmaxf(acc, 0.f);
  }
  __syncthreads();
  if (t < 128){
    const float4* wp = (const float4*)(g_ws + FW2 + ((size_t)br*128 + t)*256);
    const float4* xp = (const float4*)x1s;
    float acc=0.f;
    #pragma unroll 8
    for (int q=0;q<64;q++){ float4 w4=wp[q], x4=xp[q]; acc += w4.x*x4.x + w4.y*x4.y + w4.z*x4.z + w4.w*x4.w; }
    acc = (acc + g_ws[FB2+br*128+t])*s;
    acc = g_ws[FG2+br*128+t]*acc + g_ws[FBE2+br*128+t];
    int oi = ((size_t)br*BB + b)*128 + t;
    if (oi < out_size) out[oi] = fmaxf(acc,0.f);
  }
}

// ---------------- launch (R7: SA2 -> MFMA bf16) ----------------
extern "C" void kernel_launch(void* const* d_in, const int* in_sizes, int n_in,
                              void* d_out, int out_size, void* d_ws, size_t ws_size,
                              hipStream_t stream) {
  (void)d_ws; (void)ws_size;
  if (n_in < 21) return;
  if (in_sizes[0] != BB*3*NN) return;
  float* out = (float*)d_out;

  ParamPtrs pp;
  for (int i=0;i<20;i++) pp.p[i] = d_in[i+1];

  init_flags_kernel<<<1,64,0,stream>>>();
  detect_dtype_kernel<<<1,256,0,stream>>>(d_in[0]);
  cvt_params_kernel<<<512,256,0,stream>>>(pp, 0);
  prep_xyz_kernel<<<(BB*NN)/256,256,0,stream>>>(d_in[0], 0);
  scan_check_kernel<<<128,256,0,stream>>>(OFF_XS, 3*BB*NN);
  scan_check_kernel<<<128,256,0,stream>>>(FW1, 3*256*512);
  resolve_flip_kernel<<<1,64,0,stream>>>();
  cvt_params_kernel<<<512,256,0,stream>>>(pp, 1);     // gated on g_flip
  prep_xyz_kernel<<<(BB*NN)/256,256,0,stream>>>(d_in[0], 1);
  cvt_bf16_kernel<<<256,256,0,stream>>>();

  fps1_kernel<<<BB,256,0,stream>>>();
  fps2_kernel<<<BB,64,0,stream>>>();
  knn1_kernel<<<4096,256,0,stream>>>();
  knn2_kernel<<<1024,256,0,stream>>>();
  sa1_kernel<<<dim3(2048,3),128,0,stream>>>();

  sa2_mfma_kernel<16><<<4096,256,0,stream>>>(0);
  sa2_mfma_kernel<32><<<4096,256,0,stream>>>(1);
  sa2_mfma_kernel<48><<<4096,256,0,stream>>>(2);

  sa3l1_kernel<<<dim3(128,3),512,0,stream>>>();
  sa3l2_kernel<<<dim3(128,3),512,0,stream>>>();
  combine_kernel<<<192,256,0,stream>>>(out, out_size);
  fc_kernel<<<96,256,0,stream>>>(out, out_size);
}

// Round 8
// 1755.697 us; speedup vs baseline: 1.8313x; 1.1723x over previous
//
#include <hip/hip_runtime.h>
#include <hip/hip_bf16.h>
#include <math.h>

#define DEVI __device__ __forceinline__

static constexpr int BB = 32, NN = 2048, S1 = 512, S2 = 128;

typedef float f32x4 __attribute__((ext_vector_type(4)));
typedef short s16x8 __attribute__((ext_vector_type(8)));   // 8 bf16 bit-patterns (4 VGPRs)

// ---------------- static workspace layout (float units) ----------------
static constexpr size_t OFF_XS   = 0;
static constexpr size_t OFF_YS   = OFF_XS + (size_t)BB*NN;
static constexpr size_t OFF_ZS   = OFF_YS + (size_t)BB*NN;
static constexpr size_t OFF_SSQ  = OFF_ZS + (size_t)BB*NN;
static constexpr size_t OFF_NX1X = OFF_SSQ + (size_t)BB*NN;
static constexpr size_t OFF_NX1Y = OFF_NX1X + (size_t)BB*S1;
static constexpr size_t OFF_NX1Z = OFF_NX1Y + (size_t)BB*S1;
static constexpr size_t OFF_NX2X = OFF_NX1Z + (size_t)BB*S1;
static constexpr size_t OFF_NX2Y = OFF_NX2X + (size_t)BB*S2;
static constexpr size_t OFF_NX2Z = OFF_NX2Y + (size_t)BB*S2;
static constexpr size_t OFF_CODE = OFF_NX2Z + (size_t)BB*S2;          // 3*32*512
static constexpr size_t OFF_O3P  = OFF_CODE + (size_t)3*BB*512;       // 3*32*4*512
static constexpr size_t OFF_P1   = OFF_O3P + (size_t)3*BB*4*512;      // 3*(32*512)*128
static constexpr size_t OFF_X3   = OFF_P1 + (size_t)3*BB*S1*128;      // 3*4096*260
static constexpr size_t OFF_H3   = OFF_X3 + (size_t)3*BB*S2*260;      // (unused after R8)
static constexpr size_t OFF_W    = OFF_H3 + (size_t)3*BB*S2*512;
// weights (f32, padded)
static constexpr size_t W1A  = OFF_W;
static constexpr size_t B1A  = W1A + 3*64*6;
static constexpr size_t W2A  = B1A + 3*64;
static constexpr size_t B2A  = W2A + 3*128*64;
static constexpr size_t W1B  = B2A + 3*128;
static constexpr size_t B1B  = W1B + 3*128*132;
static constexpr size_t W2B  = B1B + 3*128;
static constexpr size_t B2B  = W2B + 3*256*128;
static constexpr size_t W1C  = B2B + 3*256;
static constexpr size_t B1C  = W1C + 3*512*260;
static constexpr size_t W2C  = B1C + 3*512;
static constexpr size_t B2C  = W2C + 3*512*512;
static constexpr size_t FW1  = B2C + 3*512;
static constexpr size_t FB1  = FW1 + 3*256*512;
static constexpr size_t FG1  = FB1 + 3*256;
static constexpr size_t FBE1 = FG1 + 3*256;
static constexpr size_t FW2  = FBE1 + 3*256;
static constexpr size_t FB2  = FW2 + 3*128*256;
static constexpr size_t FG2  = FB2 + 3*128;
static constexpr size_t FBE2 = FG2 + 3*128;
static constexpr size_t OFF_KNN1 = FBE2 + 3*128;                      // int region
static constexpr size_t OFF_KNN2 = OFF_KNN1 + (size_t)BB*S1*16;
// bf16 weight copies (as shorts inside the float array)
static constexpr size_t OFF_W1BF = OFF_KNN2 + (size_t)BB*S2*48;       // 3*128*160 bf16
static constexpr size_t OFF_W2BF = OFF_W1BF + 30720;                  // 3*256*128 bf16
// R8: bf16 hi/lo buffers for SA3 MFMA
static constexpr size_t OFF_W1CBH = OFF_W2BF + 49152;                 // 3*512*288 shorts
static constexpr size_t OFF_W1CBL = OFF_W1CBH + 221184;
static constexpr size_t OFF_W2CBH = OFF_W1CBL + 221184;               // 3*512*512 shorts
static constexpr size_t OFF_W2CBL = OFF_W2CBH + 393216;
static constexpr size_t OFF_X3BH  = OFF_W2CBL + 393216;               // 3*4096*288 shorts
static constexpr size_t OFF_X3BL  = OFF_X3BH + 1769472;
static constexpr size_t OFF_H3BH  = OFF_X3BL + 1769472;               // 3*4096*512 shorts
static constexpr size_t OFF_H3BL  = OFF_H3BH + 3145728;
static constexpr size_t WS_FLOATS = OFF_H3BL + 3145728;               // ~29.8M floats = 119 MB

__device__ __align__(16) float g_ws[WS_FLOATS];
__device__ int g_is_f32;
__device__ int g_flip;
__device__ int g_bad;
__device__ int g_nz;

DEVI float bf2f(const __hip_bfloat16 v){ return __bfloat162float(v); }
DEVI float rn_add(float a, float b){ return __fadd_rn(a,b); }
DEVI float rn_mul(float a, float b){ return __fmul_rn(a,b); }
DEVI float rn_sub(float a, float b){ return __fsub_rn(a,b); }
DEVI float sq3(float x,float y,float z){ return rn_add(rn_add(rn_mul(x,x),rn_mul(y,y)),rn_mul(z,z)); }

DEVI float ldany(const void* s, size_t i, int isf){
  return isf ? ((const float*)s)[i] : bf2f(((const __hip_bfloat16*)s)[i]);
}
DEVI unsigned short f2bf(float f){
  unsigned u = __float_as_uint(f);
  unsigned r = (u + 0x7FFFu + ((u>>16)&1u)) >> 16;
  return (unsigned short)r;
}
DEVI float bfbits2f(unsigned short h){ return __uint_as_float(((unsigned)h)<<16); }
DEVI void mfma16(f32x4& d, s16x8 a, s16x8 b){
  asm volatile("v_mfma_f32_16x16x32_bf16 %0, %1, %2, %0" : "+v"(d) : "v"(a), "v"(b));
}
DEVI void mfma_guard(f32x4& d){
  asm volatile("s_nop 7\n\ts_nop 7\n\ts_nop 2" : "+v"(d));
}

// ---------------- init ----------------
__global__ __launch_bounds__(64) void init_flags_kernel(){
  if (threadIdx.x==0){ g_is_f32=0; g_flip=0; g_bad=0; g_nz=0; }
}

// ---------------- dtype detection ----------------
__global__ __launch_bounds__(256) void detect_dtype_kernel(const void* __restrict__ pc){
  __shared__ int s_cnt[256];
  const unsigned short* h = (const unsigned short*)pc;
  int t = threadIdx.x; int weird = 0;
  for (int i=t; i<4096; i+=256){
    unsigned short v = h[2*i];
    int e = (v >> 7) & 0xFF;
    if (e == 0xFF || e < 90 || e > 140) weird++;
  }
  s_cnt[t] = weird; __syncthreads();
  for (int o=128;o>0;o>>=1){ if (t<o) s_cnt[t]+=s_cnt[t+o]; __syncthreads(); }
  if (t==0) g_is_f32 = (s_cnt[0] > 1024) ? 1 : 0;
}

// ---------------- param conversion ----------------
struct ParamPtrs { const void* p[20]; };

DEVI void cvt_arr(const void* s, float* d, int n, int g, int gs, int isf){
  for (int i=g;i<n;i+=gs) d[i] = ldany(s,i,isf);
}
DEVI void cvt_pad(const void* s, float* d, int rows, int cin, int cinp, int g, int gs, int isf){
  int tot = rows*cinp;
  for (int i=g;i<tot;i+=gs){ int r=i/cinp, c=i%cinp; d[i] = (c<cin)? ldany(s,(size_t)r*cin+c,isf) : 0.f; }
}

__global__ __launch_bounds__(256) void cvt_params_kernel(ParamPtrs pp, int mode){
  if (mode==1 && g_flip==0) return;
  const int isf = g_is_f32 ^ mode;
  int g = blockIdx.x*256 + threadIdx.x; int gs = gridDim.x*256;
  float* ws = g_ws;
  cvt_arr(pp.p[0],  ws+W1A, 3*64*6, g, gs, isf);
  cvt_arr(pp.p[1],  ws+B1A, 3*64, g, gs, isf);
  cvt_arr(pp.p[2],  ws+W2A, 3*128*64, g, gs, isf);
  cvt_arr(pp.p[3],  ws+B2A, 3*128, g, gs, isf);
  cvt_pad(pp.p[4],  ws+W1B, 3*128, 131, 132, g, gs, isf);
  cvt_arr(pp.p[5],  ws+B1B, 3*128, g, gs, isf);
  cvt_arr(pp.p[6],  ws+W2B, 3*256*128, g, gs, isf);
  cvt_arr(pp.p[7],  ws+B2B, 3*256, g, gs, isf);
  cvt_pad(pp.p[8],  ws+W1C, 3*512, 259, 260, g, gs, isf);
  cvt_arr(pp.p[9],  ws+B1C, 3*512, g, gs, isf);
  cvt_arr(pp.p[10], ws+W2C, 3*512*512, g, gs, isf);
  cvt_arr(pp.p[11], ws+B2C, 3*512, g, gs, isf);
  cvt_arr(pp.p[12], ws+FW1, 3*256*512, g, gs, isf);
  cvt_arr(pp.p[13], ws+FB1, 3*256, g, gs, isf);
  cvt_arr(pp.p[14], ws+FG1, 3*256, g, gs, isf);
  cvt_arr(pp.p[15], ws+FBE1,3*256, g, gs, isf);
  cvt_arr(pp.p[16], ws+FW2, 3*128*256, g, gs, isf);
  cvt_arr(pp.p[17], ws+FB2, 3*128, g, gs, isf);
  cvt_arr(pp.p[18], ws+FG2, 3*128, g, gs, isf);
  cvt_arr(pp.p[19], ws+FBE2,3*128, g, gs, isf);
}

__global__ __launch_bounds__(256) void prep_xyz_kernel(const void* __restrict__ pc, int mode){
  if (mode==1 && g_flip==0) return;
  const int isf = g_is_f32 ^ mode;
  int i = blockIdx.x*256 + threadIdx.x;
  int b = i >> 11, n = i & 2047;
  float x = ldany(pc, (size_t)(b*3+0)*2048 + n, isf);
  float y = ldany(pc, (size_t)(b*3+1)*2048 + n, isf);
  float z = ldany(pc, (size_t)(b*3+2)*2048 + n, isf);
  g_ws[OFF_XS+i]=x; g_ws[OFF_YS+i]=y; g_ws[OFF_ZS+i]=z;
  g_ws[OFF_SSQ+i]=sq3(x,y,z);
}

// ---------------- sanity scan -> g_bad/g_nz ----------------
__global__ __launch_bounds__(256) void scan_check_kernel(size_t off, int n){
  int g = blockIdx.x*256 + threadIdx.x; int gs = gridDim.x*256;
  int bad=0, nz=0;
  for (int i=g;i<n;i+=gs){
    float v = g_ws[off + i];
    if (v != v || fabsf(v) > 1e4f) bad=1;
    if (fabsf(v) > 1e-20f) nz=1;
  }
  unsigned long long mb = __ballot(bad), mn = __ballot(nz);
  if ((threadIdx.x & 63)==0){
    if (mb) atomicOr(&g_bad, 1);
    if (mn) atomicOr(&g_nz, 1);
  }
}

__global__ __launch_bounds__(64) void resolve_flip_kernel(){
  if (threadIdx.x==0){
    g_flip = (g_bad || !g_nz) ? 1 : 0;
    g_bad = 0; g_nz = 0;
  }
}

// ---------------- bf16 weight copies ----------------
__global__ __launch_bounds__(256) void cvt_bf16_kernel(){
  int g = blockIdx.x*256 + threadIdx.x; int gs = gridDim.x*256;
  unsigned short* w1d = (unsigned short*)(g_ws + OFF_W1BF);
  for (int i=g; i<3*128*160; i+=gs){
    int br = i/(128*160); int rem = i%(128*160); int h = rem/160; int c = rem%160;
    float v = (c<132) ? g_ws[W1B + ((size_t)br*128 + h)*132 + c] : 0.f;
    w1d[i] = f2bf(v);
  }
  unsigned short* w2d = (unsigned short*)(g_ws + OFF_W2BF);
  for (int i=g; i<3*256*128; i+=gs){
    w2d[i] = f2bf(g_ws[W2B + i]);
  }
  // SA3 weights hi/lo (W1C padded 260->288)
  unsigned short* w1ch = (unsigned short*)(g_ws + OFF_W1CBH);
  unsigned short* w1cl = (unsigned short*)(g_ws + OFF_W1CBL);
  for (int i=g; i<3*512*288; i+=gs){
    int br = i/(512*288); int rem = i%(512*288); int n = rem/288; int c = rem%288;
    float v = (c<260) ? g_ws[W1C + ((size_t)br*512 + n)*260 + c] : 0.f;
    unsigned short hi = f2bf(v);
    w1ch[i] = hi; w1cl[i] = f2bf(v - bfbits2f(hi));
  }
  unsigned short* w2ch = (unsigned short*)(g_ws + OFF_W2CBH);
  unsigned short* w2cl = (unsigned short*)(g_ws + OFF_W2CBL);
  for (int i=g; i<3*512*512; i+=gs){
    float v = g_ws[W2C + i];
    unsigned short hi = f2bf(v);
    w2ch[i] = hi; w2cl[i] = f2bf(v - bfbits2f(hi));
  }
}

// ---------------- FPS1: single wave, no barriers ----------------
__global__ __launch_bounds__(64) void fps1_kernel(){
  const int b = blockIdx.x, lane = threadIdx.x;
  const float* xs = g_ws + OFF_XS + (size_t)b*NN;
  const float* ys = g_ws + OFF_YS + (size_t)b*NN;
  const float* zs = g_ws + OFF_ZS + (size_t)b*NN;
  float* nx = g_ws + OFF_NX1X + (size_t)b*S1;
  float* ny = g_ws + OFF_NX1Y + (size_t)b*S1;
  float* nz = g_ws + OFF_NX1Z + (size_t)b*S1;
  __shared__ float xl[NN], yl[NN], zl[NN];
  float px[32],py[32],pz[32],dist[32];
  #pragma unroll
  for (int j=0;j<32;j++){
    int n=j*64+lane;
    px[j]=xs[n]; py[j]=ys[n]; pz[j]=zs[n]; dist[j]=1e10f;
    xl[n]=px[j]; yl[n]=py[j]; zl[n]=pz[j];
  }
  __syncthreads();    // single wave: compiles to waitcnt, ensures LDS visible
  float lx = xl[0], ly = yl[0], lz = zl[0];
  if (lane==0){ nx[0]=lx; ny[0]=ly; nz[0]=lz; }
  for (int i=1;i<S1;i++){
    float best=-1.f; int bidx=0x7fffffff;
    #pragma unroll
    for (int j=0;j<32;j++){
      float dx=rn_sub(px[j],lx), dy=rn_sub(py[j],ly), dz=rn_sub(pz[j],lz);
      float d = sq3(dx,dy,dz);
      float nd = fminf(dist[j], d); dist[j]=nd;
      if (nd > best){ best=nd; bidx=j*64+lane; }
    }
    #pragma unroll
    for (int off=32; off>=1; off>>=1){
      float ov = __shfl_xor(best, off); int oi = __shfl_xor(bidx, off);
      if (ov > best || (ov == best && oi < bidx)){ best=ov; bidx=oi; }
    }
    lx = xl[bidx]; ly = yl[bidx]; lz = zl[bidx];   // uniform LDS broadcast
    if (lane==0){ nx[i]=lx; ny[i]=ly; nz[i]=lz; }
  }
}

// ---------------- FPS2: single wave, LDS broadcast ----------------
__global__ __launch_bounds__(64) void fps2_kernel(){
  const int b = blockIdx.x, lane = threadIdx.x;
  const float* xs = g_ws + OFF_NX1X + (size_t)b*S1;
  const float* ys = g_ws + OFF_NX1Y + (size_t)b*S1;
  const float* zs = g_ws + OFF_NX1Z + (size_t)b*S1;
  float* nx = g_ws + OFF_NX2X + (size_t)b*S2;
  float* ny = g_ws + OFF_NX2Y + (size_t)b*S2;
  float* nz = g_ws + OFF_NX2Z + (size_t)b*S2;
  __shared__ float xl[S1], yl[S1], zl[S1];
  float px[8],py[8],pz[8],dist[8];
  #pragma unroll
  for (int j=0;j<8;j++){
    int n=j*64+lane;
    px[j]=xs[n]; py[j]=ys[n]; pz[j]=zs[n]; dist[j]=1e10f;
    xl[n]=px[j]; yl[n]=py[j]; zl[n]=pz[j];
  }
  __syncthreads();
  float lx = xl[0], ly = yl[0], lz = zl[0];
  if (lane==0){ nx[0]=lx; ny[0]=ly; nz[0]=lz; }
  for (int i=1;i<S2;i++){
    float best=-1.f; int bidx=0x7fffffff;
    #pragma unroll
    for (int j=0;j<8;j++){
      float dx=rn_sub(px[j],lx), dy=rn_sub(py[j],ly), dz=rn_sub(pz[j],lz);
      float d = sq3(dx,dy,dz);
      float nd = fminf(dist[j], d); dist[j]=nd;
      if (nd > best){ best=nd; bidx=j*64+lane; }
    }
    #pragma unroll
    for (int off=32; off>=1; off>>=1){
      float ov = __shfl_xor(best, off); int oi = __shfl_xor(bidx, off);
      if (ov > best || (ov == best && oi < bidx)){ best=ov; bidx=oi; }
    }
    lx = xl[bidx]; ly = yl[bidx]; lz = zl[bidx];
    if (lane==0){ nx[i]=lx; ny[i]=ly; nz[i]=lz; }
  }
}

// ---------------- KNN ----------------
__global__ __launch_bounds__(256) void knn1_kernel(){
  int wid = (blockIdx.x*256 + threadIdx.x) >> 6;
  int lane = threadIdx.x & 63;
  int b = wid >> 9;
  const float* xs = g_ws + OFF_XS + (size_t)b*NN;
  const float* ys = g_ws + OFF_YS + (size_t)b*NN;
  const float* zs = g_ws + OFF_ZS + (size_t)b*NN;
  const float* sq = g_ws + OFF_SSQ + (size_t)b*NN;
  float cx = g_ws[OFF_NX1X + wid], cy = g_ws[OFF_NX1Y + wid], cz = g_ws[OFF_NX1Z + wid];
  float sc = sq3(cx,cy,cz);
  float d[32];
  #pragma unroll
  for (int c=0;c<32;c++){
    int n = c*64 + lane;
    float x=xs[n], y=ys[n], z=zs[n];
    float dot = rn_add(rn_add(rn_mul(cx,x),rn_mul(cy,y)),rn_mul(cz,z));
    d[c] = rn_sub(rn_add(sc,sq[n]), rn_mul(2.f,dot));
  }
  unsigned sel=0;
  int* out = (int*)(g_ws + OFF_KNN1) + (size_t)wid*16;
  for (int r=0;r<16;r++){
    float bd=3.0e38f; int bi=0x7fffffff;
    #pragma unroll
    for (int c=0;c<32;c++){
      bool ok = ((sel>>c)&1u)==0u;
      if (ok && d[c] < bd){ bd=d[c]; bi=c*64+lane; }
    }
    #pragma unroll
    for (int off=32; off>=1; off>>=1){
      float od=__shfl_xor(bd,off); int oi=__shfl_xor(bi,off);
      if (od < bd || (od==bd && oi<bi)){ bd=od; bi=oi; }
    }
    if (lane == (bi & 63)) sel |= 1u << ((unsigned)(bi & 2047) >> 6);
    if (lane == 0) out[r] = bi;
  }
}

__global__ __launch_bounds__(256) void knn2_kernel(){
  int wid = (blockIdx.x*256 + threadIdx.x) >> 6;
  int lane = threadIdx.x & 63;
  int b = wid >> 7;
  const float* xs = g_ws + OFF_NX1X + (size_t)b*S1;
  const float* ys = g_ws + OFF_NX1Y + (size_t)b*S1;
  const float* zs = g_ws + OFF_NX1Z + (size_t)b*S1;
  float cx = g_ws[OFF_NX2X + wid], cy = g_ws[OFF_NX2Y + wid], cz = g_ws[OFF_NX2Z + wid];
  float sc = sq3(cx,cy,cz);
  float d[8];
  #pragma unroll
  for (int c=0;c<8;c++){
    int n = c*64 + lane;
    float x=xs[n], y=ys[n], z=zs[n];
    float sx = sq3(x,y,z);
    float dot = rn_add(rn_add(rn_mul(cx,x),rn_mul(cy,y)),rn_mul(cz,z));
    d[c] = rn_sub(rn_add(sc,sx), rn_mul(2.f,dot));
  }
  unsigned sel=0;
  int* out = (int*)(g_ws + OFF_KNN2) + (size_t)wid*48;
  for (int r=0;r<48;r++){
    float bd=3.0e38f; int bi=0x7fffffff;
    #pragma unroll
    for (int c=0;c<8;c++){
      bool ok = ((sel>>c)&1u)==0u;
      if (ok && d[c] < bd){ bd=d[c]; bi=c*64+lane; }
    }
    #pragma unroll
    for (int off=32; off>=1; off>>=1){
      float od=__shfl_xor(bd,off); int oi=__shfl_xor(bi,off);
      if (od < bd || (od==bd && oi<bi)){ bd=od; bi=oi; }
    }
    if (lane == (bi & 63)) sel |= 1u << ((unsigned)(bi & 511) >> 6);
    if (lane == 0) out[r] = bi;
  }
}

// ---------------- SA1 fused (unchanged f32) ----------------
__global__ __launch_bounds__(128) void sa1_kernel(){
  int br = blockIdx.y; int t = threadIdx.x;
  __shared__ float w1s[384]; __shared__ float b1s[64]; __shared__ float b2s[128];
  __shared__ float xg[96]; __shared__ float hs[1024]; __shared__ float ctr[3];
  __shared__ int idxg[16];
  const float* w1g = g_ws + W1A + (size_t)br*384;
  for (int i=t;i<384;i+=128) w1s[i]=w1g[i];
  if (t<64) b1s[t] = g_ws[B1A + br*64 + t];
  b2s[t] = g_ws[B2A + br*128 + t];
  float4 w2r[16];
  const float4* w2p = (const float4*)(g_ws + W2A + ((size_t)br*128 + t)*64);
  #pragma unroll
  for (int q=0;q<16;q++) w2r[q]=w2p[q];
  const int* kn = (const int*)(g_ws + OFF_KNN1);
  __syncthreads();
  for (int g=0; g<8; g++){
    int gid = blockIdx.x*8 + g; int b = gid >> 9;
    if (t<16) idxg[t] = kn[(size_t)gid*16 + t] & (NN-1);
    if (t<3)  ctr[t] = (t==0)? g_ws[OFF_NX1X+gid] : (t==1)? g_ws[OFF_NX1Y+gid] : g_ws[OFF_NX1Z+gid];
    __syncthreads();
    if (t<96){
      int k=t/6, cc=t%6; int idx = idxg[k]; size_t gl = (size_t)b*NN + idx;
      float v;
      if (cc<3){ const float* A = (cc==0)? g_ws+OFF_XS : (cc==1)? g_ws+OFF_YS : g_ws+OFF_ZS; v = A[gl] - ctr[cc]; }
      else { int c2=cc-3; const float* A = (c2==0)? g_ws+OFF_XS : (c2==1)? g_ws+OFF_YS : g_ws+OFF_ZS; v = A[gl]; }
      xg[t]=v;
    }
    __syncthreads();
    for (int e=t; e<1024; e+=128){
      int k=e>>6, h=e&63;
      float acc=b1s[h];
      #pragma unroll
      for (int c=0;c<6;c++) acc += xg[k*6+c]*w1s[h*6+c];
      hs[e] = fmaxf(acc,0.f);
    }
    __syncthreads();
    float m=-3.4e38f;
    for (int k=0;k<16;k++){
      const float4* hp = (const float4*)(hs + k*64);
      float acc=b2s[t];
      #pragma unroll
      for (int q=0;q<16;q++){ float4 h4=hp[q]; acc += h4.x*w2r[q].x + h4.y*w2r[q].y + h4.z*w2r[q].z + h4.w*w2r[q].w; }
      m=fmaxf(m,acc);
    }
    g_ws[OFF_P1 + ((size_t)br*16384 + gid)*128 + t] = m;
    __syncthreads();
  }
}

// ---------------- SA2 fused via MFMA bf16 (unchanged from R7) ----------------
template<int K>
__global__ __launch_bounds__(256) void sa2_mfma_kernel(int br){
  constexpr int MT = K/16;
  const int g2 = blockIdx.x;
  const int b = g2 >> 7;
  const int t = threadIdx.x;
  const int wave = t >> 6, lane = t & 63, quad = lane >> 4, l16 = lane & 15;
  __shared__ __align__(16) short Xb[K*168];
  __shared__ __align__(16) short Hb[K*136];
  __shared__ float ctr[3];
  __shared__ int idxs[K];
  const int* kn2 = (const int*)(g_ws + OFF_KNN2) + (size_t)g2*48;
  if (t < K) idxs[t] = kn2[t] & (S1-1);
  if (t < 3) ctr[t] = g_ws[(t==0?OFF_NX2X:(t==1?OFF_NX2Y:OFF_NX2Z)) + g2];
  __syncthreads();
  const float* p1b = g_ws + OFF_P1 + (size_t)br*16384*128;
  for (int e=t; e<K*168; e+=256){
    int k = e/168, j = e%168;
    int idx = idxs[k];
    float v;
    if (j < 3){
      const float* A = (j==0)? g_ws+OFF_NX1X : (j==1)? g_ws+OFF_NX1Y : g_ws+OFF_NX1Z;
      v = A[(size_t)b*S1 + idx] - ctr[j];
    } else if (j < 131){
      v = p1b[((size_t)b*S1 + idx)*128 + (j-3)];
    } else v = 0.f;
    Xb[e] = (short)f2bf(v);
  }
  __syncthreads();
  {
    const short* w1bf = (const short*)(g_ws + OFF_W1BF) + (size_t)br*128*160;
    const float* b1 = g_ws + B1B + br*128;
    for (int ni = wave; ni < 8; ni += 4){
      int h = ni*16 + l16;
      s16x8 bfr[5];
      #pragma unroll
      for (int ks=0;ks<5;ks++) bfr[ks] = *(const s16x8*)(w1bf + (size_t)h*160 + ks*32 + quad*8);
      float bias = b1[h];
      #pragma unroll
      for (int m=0; m<MT; m++){
        f32x4 acc = {0.f,0.f,0.f,0.f};
        #pragma unroll
        for (int ks=0;ks<5;ks++){
          s16x8 a = *(const s16x8*)(&Xb[(m*16 + l16)*168 + ks*32 + quad*8]);
          mfma16(acc, a, bfr[ks]);
        }
        mfma_guard(acc);
        #pragma unroll
        for (int r=0;r<4;r++){
          int row = m*16 + quad*4 + r;
          float hv = fmaxf(acc[r] + bias, 0.f);
          Hb[row*136 + ni*16 + l16] = (short)f2bf(hv);
        }
      }
    }
  }
  __syncthreads();
  {
    const short* w2bf = (const short*)(g_ws + OFF_W2BF) + (size_t)br*256*128;
    const float* b2 = g_ws + B2B + br*256;
    float* X3row = g_ws + OFF_X3 + ((size_t)br*4096 + g2)*260;
    for (int ni = wave; ni < 16; ni += 4){
      int o = ni*16 + l16;
      s16x8 bfr[4];
      #pragma unroll
      for (int ks=0;ks<4;ks++) bfr[ks] = *(const s16x8*)(w2bf + (size_t)o*128 + ks*32 + quad*8);
      float vmax = -3.4e38f;
      #pragma unroll
      for (int m=0; m<MT; m++){
        f32x4 acc = {0.f,0.f,0.f,0.f};
        #pragma unroll
        for (int ks=0;ks<4;ks++){
          s16x8 a = *(const s16x8*)(&Hb[(m*16 + l16)*136 + ks*32 + quad*8]);
          mfma16(acc, a, bfr[ks]);
        }
        mfma_guard(acc);
        #pragma unroll
        for (int r=0;r<4;r++) vmax = fmaxf(vmax, acc[r]);
      }
      vmax = fmaxf(vmax, __shfl_xor(vmax, 16));
      vmax = fmaxf(vmax, __shfl_xor(vmax, 32));
      if (quad == 0) X3row[3 + o] = vmax + b2[o];
    }
    if (t < 3) X3row[t] = ctr[t];
    if (t == 3) X3row[259] = 0.f;
  }
}

// ---------------- X3 -> bf16 hi/lo (260 -> 288 pad) ----------------
__global__ __launch_bounds__(256) void x3bf_kernel(){
  int g = blockIdx.x*256 + threadIdx.x; int gs = gridDim.x*256;
  unsigned short* xh = (unsigned short*)(g_ws + OFF_X3BH);
  unsigned short* xl = (unsigned short*)(g_ws + OFF_X3BL);
  for (int i=g; i<3*4096*288; i+=gs){
    int r = i/288, c = i%288;
    float v = (c<260) ? g_ws[OFF_X3 + (size_t)r*260 + c] : 0.f;
    unsigned short hi = f2bf(v);
    xh[i] = hi; xl[i] = f2bf(v - bfbits2f(hi));
  }
}

// ---------------- SA3 layer1 via MFMA (hi/lo split): 288 -> 512 relu ----------------
__global__ __launch_bounds__(256) void sa3l1_mfma_kernel(){
  const int br = blockIdx.y; const int r0 = blockIdx.x*32;
  const int t = threadIdx.x;
  const int wave = t >> 6, lane = t & 63, quad = lane >> 4, l16 = lane & 15;
  const short* xh = (const short*)(g_ws + OFF_X3BH) + (size_t)(br*4096 + r0)*288;
  const short* xl = (const short*)(g_ws + OFF_X3BL) + (size_t)(br*4096 + r0)*288;
  const short* wh = (const short*)(g_ws + OFF_W1CBH) + (size_t)br*512*288;
  const short* wl = (const short*)(g_ws + OFF_W1CBL) + (size_t)br*512*288;
  const float* bias = g_ws + B1C + br*512;
  unsigned short* hh = (unsigned short*)(g_ws + OFF_H3BH) + (size_t)(br*4096 + r0)*512;
  unsigned short* hl = (unsigned short*)(g_ws + OFF_H3BL) + (size_t)(br*4096 + r0)*512;
  f32x4 acc[2][8];
  #pragma unroll
  for (int m=0;m<2;m++)
    #pragma unroll
    for (int ni=0;ni<8;ni++) acc[m][ni] = (f32x4){0.f,0.f,0.f,0.f};
  for (int ks=0; ks<9; ks++){
    s16x8 ah[2], al[2];
    #pragma unroll
    for (int m=0;m<2;m++){
      ah[m] = *(const s16x8*)(xh + (size_t)(m*16+l16)*288 + ks*32 + quad*8);
      al[m] = *(const s16x8*)(xl + (size_t)(m*16+l16)*288 + ks*32 + quad*8);
    }
    #pragma unroll
    for (int ni=0;ni<8;ni++){
      int n = wave*128 + ni*16 + l16;
      s16x8 bh = *(const s16x8*)(wh + (size_t)n*288 + ks*32 + quad*8);
      s16x8 bl = *(const s16x8*)(wl + (size_t)n*288 + ks*32 + quad*8);
      #pragma unroll
      for (int m=0;m<2;m++){
        mfma16(acc[m][ni], ah[m], bh);
        mfma16(acc[m][ni], ah[m], bl);
        mfma16(acc[m][ni], al[m], bh);
      }
    }
  }
  mfma_guard(acc[0][0]);
  #pragma unroll
  for (int m=0;m<2;m++){
    #pragma unroll
    for (int ni=0;ni<8;ni++){
      int col = wave*128 + ni*16 + l16;
      float bs = bias[col];
      #pragma unroll
      for (int r=0;r<4;r++){
        int row = m*16 + quad*4 + r;
        float hv = fmaxf(acc[m][ni][r] + bs, 0.f);
        unsigned short hi = f2bf(hv);
        hh[(size_t)row*512 + col] = hi;
        hl[(size_t)row*512 + col] = f2bf(hv - bfbits2f(hi));
      }
    }
  }
}

// ---------------- SA3 layer2 via MFMA (hi/lo split): 512 -> 512, partial max over 32 rows ----------------
__global__ __launch_bounds__(256) void sa3l2_mfma_kernel(){
  const int br = blockIdx.y; const int b = blockIdx.x>>2; const int part = blockIdx.x&3;
  const int t = threadIdx.x;
  const int wave = t >> 6, lane = t & 63, quad = lane >> 4, l16 = lane & 15;
  const int row0 = b*128 + part*32;
  const short* ahp = (const short*)(g_ws + OFF_H3BH) + (size_t)(br*4096 + row0)*512;
  const short* alp = (const short*)(g_ws + OFF_H3BL) + (size_t)(br*4096 + row0)*512;
  const short* wh = (const short*)(g_ws + OFF_W2CBH) + (size_t)br*512*512;
  const short* wl = (const short*)(g_ws + OFF_W2CBL) + (size_t)br*512*512;
  f32x4 acc[2][8];
  #pragma unroll
  for (int m=0;m<2;m++)
    #pragma unroll
    for (int ni=0;ni<8;ni++) acc[m][ni] = (f32x4){0.f,0.f,0.f,0.f};
  for (int ks=0; ks<16; ks++){
    s16x8 ah[2], al[2];
    #pragma unroll
    for (int m=0;m<2;m++){
      ah[m] = *(const s16x8*)(ahp + (size_t)(m*16+l16)*512 + ks*32 + quad*8);
      al[m] = *(const s16x8*)(alp + (size_t)(m*16+l16)*512 + ks*32 + quad*8);
    }
    #pragma unroll
    for (int ni=0;ni<8;ni++){
      int n = wave*128 + ni*16 + l16;
      s16x8 bh = *(const s16x8*)(wh + (size_t)n*512 + ks*32 + quad*8);
      s16x8 bl = *(const s16x8*)(wl + (size_t)n*512 + ks*32 + quad*8);
      #pragma unroll
      for (int m=0;m<2;m++){
        mfma16(acc[m][ni], ah[m], bh);
        mfma16(acc[m][ni], ah[m], bl);
        mfma16(acc[m][ni], al[m], bh);
      }
    }
  }
  mfma_guard(acc[0][0]);
  #pragma unroll
  for (int ni=0;ni<8;ni++){
    float vmax = -3.4e38f;
    #pragma unroll
    for (int m=0;m<2;m++)
      #pragma unroll
      for (int r=0;r<4;r++) vmax = fmaxf(vmax, acc[m][ni][r]);
    vmax = fmaxf(vmax, __shfl_xor(vmax, 16));
    vmax = fmaxf(vmax, __shfl_xor(vmax, 32));
    if (quad == 0){
      int col = wave*128 + ni*16 + l16;
      g_ws[OFF_O3P + (((size_t)br*BB + b)*4 + part)*512 + col] = vmax;
    }
  }
}

// ---------------- combine (f32 out) ----------------
__global__ __launch_bounds__(256) void combine_kernel(float* __restrict__ out, int out_size){
  int i = blockIdx.x*256 + threadIdx.x;
  int br = i >> 14; int rem = i & 16383; int b = rem >> 9; int o = i & 511;
  float m = -3.4e38f;
  #pragma unroll
  for (int p=0;p<4;p++){
    m = fmaxf(m, g_ws[OFF_O3P + (((size_t)br*BB + b)*4 + p)*512 + o]);
  }
  m += g_ws[B2C + br*512 + o];
  g_ws[OFF_CODE + i] = m;
  int oi = 3*BB*128 + i;
  if (oi < out_size) out[oi] = m;
}

// ---------------- FC head (f32 out) ----------------
__global__ __launch_bounds__(256) void fc_kernel(float* __restrict__ out, int out_size){
  int br = blockIdx.x >> 5; int b = blockIdx.x & 31; int t = threadIdx.x;
  __shared__ float xin[512]; __shared__ float x1s[256];
  const float* code = g_ws + OFF_CODE + ((size_t)br*BB + b)*512;
  xin[t] = code[t]; xin[t+256] = code[t+256];
  __syncthreads();
  const float s = (float)(1.0 / sqrt(1.0 + 1e-5));
  {
    const float4* wp = (const float4*)(g_ws + FW1 + ((size_t)br*256 + t)*512);
    const float4* xp = (const float4*)xin;
    float acc = 0.f;
    #pragma unroll 8
    for (int q=0;q<128;q++){ float4 w4=wp[q], x4=xp[q]; acc += w4.x*x4.x + w4.y*x4.y + w4.z*x4.z + w4.w*x4.w; }
    acc = (acc + g_ws[FB1 + br*256+t]) * s;
    acc = g_ws[FG1+br*256+t]*acc + g_ws[FBE1+br*256+t];
    x1s[t] = fmaxf(acc, 0.f);
  }
  __syncthreads();
  if (t < 128){
    const float4* wp = (const float4*)(g_ws + FW2 + ((size_t)br*128 + t)*256);
    const float4* xp = (const float4*)x1s;
    float acc=0.f;
    #pragma unroll 8
    for (int q=0;q<64;q++){ float4 w4=wp[q], x4=xp[q]; acc += w4.x*x4.x + w4.y*x4.y + w4.z*x4.z + w4.w*x4.w; }
    acc = (acc + g_ws[FB2+br*128+t])*s;
    acc = g_ws[FG2+br*128+t]*acc + g_ws[FBE2+br*128+t];
    int oi = ((size_t)br*BB + b)*128 + t;
    if (oi < out_size) out[oi] = fmaxf(acc,0.f);
  }
}

// ---------------- launch (R8: single-wave FPS + SA3 MFMA hi/lo) ----------------
extern "C" void kernel_launch(void* const* d_in, const int* in_sizes, int n_in,
                              void* d_out, int out_size, void* d_ws, size_t ws_size,
                              hipStream_t stream) {
  (void)d_ws; (void)ws_size;
  if (n_in < 21) return;
  if (in_sizes[0] != BB*3*NN) return;
  float* out = (float*)d_out;

  ParamPtrs pp;
  for (int i=0;i<20;i++) pp.p[i] = d_in[i+1];

  init_flags_kernel<<<1,64,0,stream>>>();
  detect_dtype_kernel<<<1,256,0,stream>>>(d_in[0]);
  cvt_params_kernel<<<512,256,0,stream>>>(pp, 0);
  prep_xyz_kernel<<<(BB*NN)/256,256,0,stream>>>(d_in[0], 0);
  scan_check_kernel<<<128,256,0,stream>>>(OFF_XS, 3*BB*NN);
  scan_check_kernel<<<128,256,0,stream>>>(FW1, 3*256*512);
  resolve_flip_kernel<<<1,64,0,stream>>>();
  cvt_params_kernel<<<512,256,0,stream>>>(pp, 1);     // gated on g_flip
  prep_xyz_kernel<<<(BB*NN)/256,256,0,stream>>>(d_in[0], 1);
  cvt_bf16_kernel<<<512,256,0,stream>>>();

  fps1_kernel<<<BB,64,0,stream>>>();
  fps2_kernel<<<BB,64,0,stream>>>();
  knn1_kernel<<<4096,256,0,stream>>>();
  knn2_kernel<<<1024,256,0,stream>>>();
  sa1_kernel<<<dim3(2048,3),128,0,stream>>>();

  sa2_mfma_kernel<16><<<4096,256,0,stream>>>(0);
  sa2_mfma_kernel<32><<<4096,256,0,stream>>>(1);
  sa2_mfma_kernel<48><<<4096,256,0,stream>>>(2);

  x3bf_kernel<<<3456,256,0,stream>>>();
  sa3l1_mfma_kernel<<<dim3(128,3),256,0,stream>>>();
  sa3l2_mfma_kernel<<<dim3(128,3),256,0,stream>>>();
  combine_kernel<<<192,256,0,stream>>>(out, out_size);
  fc_kernel<<<96,256,0,stream>>>(out, out_size);
}